// Round 1
// baseline (1225.503 us; speedup 1.0000x reference)
//
#include <hip/hip_runtime.h>
#include <cstdint>
#include <cstddef>

#define N_NODES 100000
#define E_EDGES 1600000
#define HCH 128
#define NHEADS 8
#define HDIM 16

constexpr int TM = 64;   // rows per block tile
constexpr int BK = 32;   // k-chunk

// C[M x 128] = A[M x 128] @ W[128 x 128] + bias (+ res)
__global__ __launch_bounds__(256) void gemm128(
    const float* __restrict__ A, const float* __restrict__ W,
    const float* __restrict__ bias, const float* __restrict__ res,
    float* __restrict__ C, int M)
{
    __shared__ float As[BK][TM];    // [k][m] transposed  (8 KB)
    __shared__ float Ws[BK][HCH];   // [k][n]             (16 KB)
    const int t = threadIdx.x;
    const int m_base = blockIdx.x * TM;
    const int tc = t & 15;          // 16 col groups of 8
    const int tr = t >> 4;          // 16 row groups of 4
    const int n0 = tc * 8;
    const int m0 = tr * 4;

    float acc[4][8];
#pragma unroll
    for (int i = 0; i < 4; i++)
#pragma unroll
        for (int j = 0; j < 8; j++) acc[i][j] = 0.f;

    for (int kc = 0; kc < HCH; kc += BK) {
        // W chunk: 32x128 floats = 1024 float4, 4 per thread, coalesced
#pragma unroll
        for (int i = 0; i < 4; i++) {
            int p  = i * 256 + t;           // 0..1023
            int kk = p >> 5;                // 0..31
            int n4 = p & 31;                // float4 column
            *(float4*)(&Ws[kk][n4 * 4]) =
                *(const float4*)(W + (size_t)(kc + kk) * HCH + n4 * 4);
        }
        // A chunk transposed: 64 rows x 32 k = 512 float4, 2 per thread
#pragma unroll
        for (int i = 0; i < 2; i++) {
            int p  = i * 256 + t;           // 0..511
            int r  = p >> 3;                // 0..63
            int kf = p & 7;                 // float4 within chunk
            int g  = m_base + r;
            float4 a4 = make_float4(0.f, 0.f, 0.f, 0.f);
            if (g < M)
                a4 = *(const float4*)(A + (size_t)g * HCH + kc + kf * 4);
            As[kf * 4 + 0][r] = a4.x;
            As[kf * 4 + 1][r] = a4.y;
            As[kf * 4 + 2][r] = a4.z;
            As[kf * 4 + 3][r] = a4.w;
        }
        __syncthreads();
#pragma unroll
        for (int k = 0; k < BK; k++) {
            float4 a4 = *(const float4*)(&As[k][m0]);
            float4 w0 = *(const float4*)(&Ws[k][n0]);
            float4 w1 = *(const float4*)(&Ws[k][n0 + 4]);
            float av[4] = {a4.x, a4.y, a4.z, a4.w};
            float wv[8] = {w0.x, w0.y, w0.z, w0.w, w1.x, w1.y, w1.z, w1.w};
#pragma unroll
            for (int i = 0; i < 4; i++)
#pragma unroll
                for (int j = 0; j < 8; j++) acc[i][j] += av[i] * wv[j];
        }
        __syncthreads();
    }

    float4 b0 = *(const float4*)(bias + n0);
    float4 b1 = *(const float4*)(bias + n0 + 4);
#pragma unroll
    for (int i = 0; i < 4; i++) {
        int g = m_base + m0 + i;
        if (g >= M) continue;
        float o[8] = {acc[i][0] + b0.x, acc[i][1] + b0.y, acc[i][2] + b0.z, acc[i][3] + b0.w,
                      acc[i][4] + b1.x, acc[i][5] + b1.y, acc[i][6] + b1.z, acc[i][7] + b1.w};
        if (res) {
            float4 r0 = *(const float4*)(res + (size_t)g * HCH + n0);
            float4 r1 = *(const float4*)(res + (size_t)g * HCH + n0 + 4);
            o[0] += r0.x; o[1] += r0.y; o[2] += r0.z; o[3] += r0.w;
            o[4] += r1.x; o[5] += r1.y; o[6] += r1.z; o[7] += r1.w;
        }
        *(float4*)(C + (size_t)g * HCH + n0)     = make_float4(o[0], o[1], o[2], o[3]);
        *(float4*)(C + (size_t)g * HCH + n0 + 4) = make_float4(o[4], o[5], o[6], o[7]);
    }
}

// scores[e][h] = dot16(q[dst[e],h,:], k[src[e],h,:]) * 0.25; online (m,l) per block/head
constexpr int SC_BLOCKS = 1280;
__global__ __launch_bounds__(256) void edge_scores(
    const float* __restrict__ q, const float* __restrict__ k,
    const int* __restrict__ src, const int* __restrict__ dst,
    float* __restrict__ scores, float2* __restrict__ block_ml)
{
    const int t = threadIdx.x;
    const int h = t & 7;
    const int estride = SC_BLOCKS * 256 / 8;  // 40960 edges per sweep
    float m = -1e30f, l = 0.f;
    for (int e = blockIdx.x * 32 + (t >> 3); e < E_EDGES; e += estride) {
        int s_ = src[e], d_ = dst[e];
        const float4* qr = (const float4*)(q + (size_t)d_ * HCH + h * HDIM);
        const float4* kr = (const float4*)(k + (size_t)s_ * HCH + h * HDIM);
        float acc = 0.f;
#pragma unroll
        for (int i = 0; i < 4; i++) {
            float4 a = qr[i], b = kr[i];
            acc += a.x * b.x + a.y * b.y + a.z * b.z + a.w * b.w;
        }
        acc *= 0.25f;  // 1/sqrt(16)
        scores[(size_t)e * 8 + h] = acc;
        float nm = fmaxf(m, acc);
        l = l * __expf(m - nm) + __expf(acc - nm);
        m = nm;
    }
    __shared__ float sm[256], sl[256];
    sm[t] = m; sl[t] = l;
    __syncthreads();
    if (t < 8) {
        float M = -1e30f, L = 0.f;
        for (int i = t; i < 256; i += 8) {
            float mm = sm[i], ll = sl[i];
            float nm = fmaxf(M, mm);
            L = L * __expf(M - nm) + ll * __expf(mm - nm);
            M = nm;
        }
        block_ml[blockIdx.x * 8 + t] = make_float2(M, L);
    }
}

// combine per-block (m,l) -> per-head (M, 1/L)
__global__ __launch_bounds__(256) void reduce_ml(
    const float2* __restrict__ block_ml, float2* __restrict__ head_ml, int nblk)
{
    const int t = threadIdx.x;
    float m = -1e30f, l = 0.f;
    for (int i = t; i < nblk * 8; i += 256) {   // i&7 == t&7 (256 % 8 == 0)
        float2 e = block_ml[i];
        float nm = fmaxf(m, e.x);
        l = l * __expf(m - nm) + e.y * __expf(e.x - nm);
        m = nm;
    }
    __shared__ float sm[256], sl[256];
    sm[t] = m; sl[t] = l;
    __syncthreads();
    if (t < 8) {
        float M = -1e30f, L = 0.f;
        for (int i = t; i < 256; i += 8) {
            float mm = sm[i], ll = sl[i];
            float nm = fmaxf(M, mm);
            L = L * __expf(M - nm) + ll * __expf(mm - nm);
            M = nm;
        }
        head_ml[t] = make_float2(M, 1.0f / L);
    }
}

// attended[dst[e]][c] += w[e][c/16] * v[src[e]][c]
constexpr int SCT_BLOCKS = 12800;
__global__ __launch_bounds__(256) void edge_scatter(
    const float* __restrict__ scores, const float* __restrict__ v,
    const int* __restrict__ src, const int* __restrict__ dst,
    const float2* __restrict__ head_ml, float* __restrict__ attended)
{
    __shared__ float2 ml[8];
    const int t = threadIdx.x;
    if (t < 8) ml[t] = head_ml[t];
    __syncthreads();
    const int c = t & 127;
    const int slot = t >> 7;       // 2 edges per block iteration
    const int h = c >> 4;
    const float M = ml[h].x, invL = ml[h].y;
    for (int e = blockIdx.x * 2 + slot; e < E_EDGES; e += SCT_BLOCKS * 2) {
        int s_ = src[e], d_ = dst[e];
        float w = __expf(scores[(size_t)e * 8 + h] - M) * invL;
        float val = w * v[(size_t)s_ * HCH + c];
        unsafeAtomicAdd(&attended[(size_t)d_ * HCH + c], val);
    }
}

extern "C" void kernel_launch(void* const* d_in, const int* in_sizes, int n_in,
                              void* d_out, int out_size, void* d_ws, size_t ws_size,
                              hipStream_t stream)
{
    const float* x  = (const float*)d_in[0];
    const int* eidx = (const int*)d_in[1];
    const float* Wq = (const float*)d_in[2];
    const float* bq = (const float*)d_in[3];
    const float* Wk = (const float*)d_in[4];
    const float* bk = (const float*)d_in[5];
    const float* Wv = (const float*)d_in[6];
    const float* bv = (const float*)d_in[7];
    const float* Wo = (const float*)d_in[8];
    const float* bo = (const float*)d_in[9];
    float* out = (float*)d_out;

    char* ws = (char*)d_ws;
    constexpr size_t SZ_NODE = (size_t)N_NODES * HCH * sizeof(float);   // 51.2 MB
    constexpr size_t SZ_SC   = (size_t)E_EDGES * NHEADS * sizeof(float); // 51.2 MB
    float*  q        = (float*)(ws);
    float*  k        = (float*)(ws + SZ_NODE);
    float*  v        = (float*)(ws + 2 * SZ_NODE);
    float*  scores   = (float*)(ws + 3 * SZ_NODE);
    float2* block_ml = (float2*)(ws + 3 * SZ_NODE + SZ_SC);
    float2* head_ml  = (float2*)(ws + 3 * SZ_NODE + SZ_SC + (size_t)SC_BLOCKS * 8 * sizeof(float2));
    float*  attended = q;  // q is dead after edge_scores; reuse its space
    const int* src = eidx;
    const int* dst = eidx + E_EDGES;

    dim3 blk(256);
    const int gblocks = (N_NODES + TM - 1) / TM;

    gemm128<<<gblocks, blk, 0, stream>>>(x, Wq, bq, nullptr, q, N_NODES);
    gemm128<<<gblocks, blk, 0, stream>>>(x, Wk, bk, nullptr, k, N_NODES);
    gemm128<<<gblocks, blk, 0, stream>>>(x, Wv, bv, nullptr, v, N_NODES);
    edge_scores<<<SC_BLOCKS, blk, 0, stream>>>(q, k, src, dst, scores, block_ml);
    reduce_ml<<<1, blk, 0, stream>>>(block_ml, head_ml, SC_BLOCKS);
    hipMemsetAsync(attended, 0, SZ_NODE, stream);
    edge_scatter<<<SCT_BLOCKS, blk, 0, stream>>>(scores, v, src, dst, head_ml, attended);
    gemm128<<<gblocks, blk, 0, stream>>>(attended, Wo, bo, x, out, N_NODES);
}

// Round 2
// 858.226 us; speedup vs baseline: 1.4279x; 1.4279x over previous
//
#include <hip/hip_runtime.h>
#include <cstdint>
#include <cstddef>

#define N_NODES 100000
#define E_EDGES 1600000
#define HCH 128
#define NHEADS 8
#define HDIM 16

constexpr int TM = 64;   // rows per block tile
constexpr int BK = 32;   // k-chunk

// ---------------- GEMM: C[M x 128] = A[M x 128] @ W[128 x 128] + bias (+ res)
__global__ __launch_bounds__(256) void gemm128(
    const float* __restrict__ A, const float* __restrict__ W,
    const float* __restrict__ bias, const float* __restrict__ res,
    float* __restrict__ C, int M)
{
    __shared__ float As[BK][TM];    // [k][m] transposed  (8 KB)
    __shared__ float Ws[BK][HCH];   // [k][n]             (16 KB)
    const int t = threadIdx.x;
    const int m_base = blockIdx.x * TM;
    const int tc = t & 15;
    const int tr = t >> 4;
    const int n0 = tc * 8;
    const int m0 = tr * 4;

    float acc[4][8];
#pragma unroll
    for (int i = 0; i < 4; i++)
#pragma unroll
        for (int j = 0; j < 8; j++) acc[i][j] = 0.f;

    for (int kc = 0; kc < HCH; kc += BK) {
#pragma unroll
        for (int i = 0; i < 4; i++) {
            int p  = i * 256 + t;
            int kk = p >> 5;
            int n4 = p & 31;
            *(float4*)(&Ws[kk][n4 * 4]) =
                *(const float4*)(W + (size_t)(kc + kk) * HCH + n4 * 4);
        }
#pragma unroll
        for (int i = 0; i < 2; i++) {
            int p  = i * 256 + t;
            int r  = p >> 3;
            int kf = p & 7;
            int g  = m_base + r;
            float4 a4 = make_float4(0.f, 0.f, 0.f, 0.f);
            if (g < M)
                a4 = *(const float4*)(A + (size_t)g * HCH + kc + kf * 4);
            As[kf * 4 + 0][r] = a4.x;
            As[kf * 4 + 1][r] = a4.y;
            As[kf * 4 + 2][r] = a4.z;
            As[kf * 4 + 3][r] = a4.w;
        }
        __syncthreads();
#pragma unroll
        for (int k = 0; k < BK; k++) {
            float4 a4 = *(const float4*)(&As[k][m0]);
            float4 w0 = *(const float4*)(&Ws[k][n0]);
            float4 w1 = *(const float4*)(&Ws[k][n0 + 4]);
            float av[4] = {a4.x, a4.y, a4.z, a4.w};
            float wv[8] = {w0.x, w0.y, w0.z, w0.w, w1.x, w1.y, w1.z, w1.w};
#pragma unroll
            for (int i = 0; i < 4; i++)
#pragma unroll
                for (int j = 0; j < 8; j++) acc[i][j] += av[i] * wv[j];
        }
        __syncthreads();
    }

    float4 b0 = *(const float4*)(bias + n0);
    float4 b1 = *(const float4*)(bias + n0 + 4);
#pragma unroll
    for (int i = 0; i < 4; i++) {
        int g = m_base + m0 + i;
        if (g >= M) continue;
        float o[8] = {acc[i][0] + b0.x, acc[i][1] + b0.y, acc[i][2] + b0.z, acc[i][3] + b0.w,
                      acc[i][4] + b1.x, acc[i][5] + b1.y, acc[i][6] + b1.z, acc[i][7] + b1.w};
        if (res) {
            float4 r0 = *(const float4*)(res + (size_t)g * HCH + n0);
            float4 r1 = *(const float4*)(res + (size_t)g * HCH + n0 + 4);
            o[0] += r0.x; o[1] += r0.y; o[2] += r0.z; o[3] += r0.w;
            o[4] += r1.x; o[5] += r1.y; o[6] += r1.z; o[7] += r1.w;
        }
        *(float4*)(C + (size_t)g * HCH + n0)     = make_float4(o[0], o[1], o[2], o[3]);
        *(float4*)(C + (size_t)g * HCH + n0 + 4) = make_float4(o[4], o[5], o[6], o[7]);
    }
}

// ---------------- counting sort by dst ----------------
constexpr int NCHUNK = (N_NODES + 2047) / 2048;   // 49

__global__ __launch_bounds__(256) void hist_kernel(
    const int* __restrict__ dst, int* __restrict__ counts)
{
    for (int e = blockIdx.x * 256 + threadIdx.x; e < E_EDGES; e += gridDim.x * 256)
        atomicAdd(&counts[dst[e]], 1);
}

// per-chunk exclusive scan (chunk = 2048), writes chunk totals
__global__ __launch_bounds__(256) void scan1_kernel(
    const int* __restrict__ counts, int* __restrict__ offsets, int* __restrict__ partials)
{
    __shared__ int s[256];
    const int t = threadIdx.x;
    const int base = blockIdx.x * 2048 + t * 8;
    int vals[8];
    int tsum = 0;
#pragma unroll
    for (int j = 0; j < 8; j++) {
        vals[j] = (base + j < N_NODES) ? counts[base + j] : 0;
        tsum += vals[j];
    }
    s[t] = tsum;
    __syncthreads();
    for (int off = 1; off < 256; off <<= 1) {
        int add = (t >= off) ? s[t - off] : 0;
        __syncthreads();
        s[t] += add;
        __syncthreads();
    }
    int run = s[t] - tsum;   // exclusive prefix for this thread
    if (t == 255) partials[blockIdx.x] = s[255];
#pragma unroll
    for (int j = 0; j < 8; j++) {
        if (base + j < N_NODES) offsets[base + j] = run;
        run += vals[j];
    }
}

__global__ void scan2_kernel(int* __restrict__ partials)
{
    if (threadIdx.x == 0 && blockIdx.x == 0) {
        int run = 0;
        for (int i = 0; i < NCHUNK; i++) {
            int v = partials[i];
            partials[i] = run;
            run += v;
        }
    }
}

__global__ __launch_bounds__(256) void scan3_kernel(
    int* __restrict__ offsets, const int* __restrict__ partials, int* __restrict__ cursor)
{
    int i = blockIdx.x * 256 + threadIdx.x;
    if (i < N_NODES) {
        int off = offsets[i] + partials[i >> 11];
        offsets[i] = off;
        cursor[i] = off;
    }
    if (i == 0) offsets[N_NODES] = E_EDGES;
}

__global__ __launch_bounds__(256) void permute_kernel(
    const int* __restrict__ src, const int* __restrict__ dst,
    int* __restrict__ cursor, int2* __restrict__ pedge)
{
    for (int e = blockIdx.x * 256 + threadIdx.x; e < E_EDGES; e += gridDim.x * 256) {
        int d = dst[e];
        int pos = atomicAdd(&cursor[d], 1);
        pedge[pos] = make_int2(src[e], d);
    }
}

// ---------------- edge scores (sorted order) + online (m,l) ----------------
constexpr int SC_BLOCKS = 1280;
__global__ __launch_bounds__(256) void edge_scores(
    const float* __restrict__ q, const float* __restrict__ k,
    const int2* __restrict__ pedge,
    float* __restrict__ scores, float2* __restrict__ block_ml)
{
    const int t = threadIdx.x;
    const int h = t & 7;
    const int estride = SC_BLOCKS * 256 / 8;
    float m = -1e30f, l = 0.f;
    for (int e = blockIdx.x * 32 + (t >> 3); e < E_EDGES; e += estride) {
        int2 sd = pedge[e];
        const float4* qr = (const float4*)(q + (size_t)sd.y * HCH + h * HDIM);
        const float4* kr = (const float4*)(k + (size_t)sd.x * HCH + h * HDIM);
        float acc = 0.f;
#pragma unroll
        for (int i = 0; i < 4; i++) {
            float4 a = qr[i], b = kr[i];
            acc += a.x * b.x + a.y * b.y + a.z * b.z + a.w * b.w;
        }
        acc *= 0.25f;  // 1/sqrt(16)
        scores[(size_t)e * 8 + h] = acc;
        float nm = fmaxf(m, acc);
        l = l * __expf(m - nm) + __expf(acc - nm);
        m = nm;
    }
    __shared__ float sm[256], sl[256];
    sm[t] = m; sl[t] = l;
    __syncthreads();
    if (t < 8) {
        float M = -1e30f, L = 0.f;
        for (int i = t; i < 256; i += 8) {
            float mm = sm[i], ll = sl[i];
            float nm = fmaxf(M, mm);
            L = L * __expf(M - nm) + ll * __expf(mm - nm);
            M = nm;
        }
        block_ml[blockIdx.x * 8 + t] = make_float2(M, L);
    }
}

__global__ __launch_bounds__(256) void reduce_ml(
    const float2* __restrict__ block_ml, float2* __restrict__ head_ml, int nblk)
{
    const int t = threadIdx.x;
    float m = -1e30f, l = 0.f;
    for (int i = t; i < nblk * 8; i += 256) {
        float2 e = block_ml[i];
        float nm = fmaxf(m, e.x);
        l = l * __expf(m - nm) + e.y * __expf(e.x - nm);
        m = nm;
    }
    __shared__ float sm[256], sl[256];
    sm[t] = m; sl[t] = l;
    __syncthreads();
    if (t < 8) {
        float M = -1e30f, L = 0.f;
        for (int i = t; i < 256; i += 8) {
            float mm = sm[i], ll = sl[i];
            float nm = fmaxf(M, mm);
            L = L * __expf(M - nm) + ll * __expf(mm - nm);
            M = nm;
        }
        head_ml[t] = make_float2(M, 1.0f / L);
    }
}

// ---------------- segment reduction: one wave per dst node, no atomics ----------------
__global__ __launch_bounds__(256) void edge_gather(
    const float* __restrict__ scores, const float* __restrict__ v,
    const int2* __restrict__ pedge, const int* __restrict__ offsets,
    const float2* __restrict__ head_ml, float* __restrict__ attended)
{
    const int t = threadIdx.x;
    const int lane = t & 63;
    const int d = blockIdx.x * 4 + (t >> 6);
    if (d >= N_NODES) return;
    const int h = lane >> 3;                 // channel pair (2*lane) -> head (2*lane)/16
    const float2 ml = head_ml[h];
    const float M = ml.x, invL = ml.y;
    const int start = offsets[d];
    const int end   = offsets[d + 1];
    float a0 = 0.f, a1 = 0.f;
    for (int i = start; i < end; i++) {
        int2 sd = pedge[i];                  // wave-uniform -> broadcast
        float w = __expf(scores[(size_t)i * 8 + h] - M) * invL;
        float2 vv = *(const float2*)(v + (size_t)sd.x * HCH + lane * 2);
        a0 += w * vv.x;
        a1 += w * vv.y;
    }
    *(float2*)(attended + (size_t)d * HCH + lane * 2) = make_float2(a0, a1);
}

extern "C" void kernel_launch(void* const* d_in, const int* in_sizes, int n_in,
                              void* d_out, int out_size, void* d_ws, size_t ws_size,
                              hipStream_t stream)
{
    const float* x  = (const float*)d_in[0];
    const int* eidx = (const int*)d_in[1];
    const float* Wq = (const float*)d_in[2];
    const float* bq = (const float*)d_in[3];
    const float* Wk = (const float*)d_in[4];
    const float* bk = (const float*)d_in[5];
    const float* Wv = (const float*)d_in[6];
    const float* bv = (const float*)d_in[7];
    const float* Wo = (const float*)d_in[8];
    const float* bo = (const float*)d_in[9];
    float* out = (float*)d_out;

    char* ws = (char*)d_ws;
    constexpr size_t SZ_NODE = (size_t)N_NODES * HCH * sizeof(float);    // 51.2 MB
    constexpr size_t SZ_SC   = (size_t)E_EDGES * NHEADS * sizeof(float); // 51.2 MB
    constexpr size_t SZ_PE   = (size_t)E_EDGES * sizeof(int2);           // 12.8 MB
    size_t off = 0;
    float*  q        = (float*)(ws + off); off += SZ_NODE;
    float*  k        = (float*)(ws + off); off += SZ_NODE;
    float*  v        = (float*)(ws + off); off += SZ_NODE;
    float*  scores   = (float*)(ws + off); off += SZ_SC;
    int2*   pedge    = (int2*)(ws + off);  off += SZ_PE;
    int*    offsets  = (int*)(ws + off);   off += ((size_t)N_NODES + 1) * 4 + 4;
    int*    cursor   = (int*)(ws + off);   off += (size_t)N_NODES * 4;
    int*    counts   = (int*)(ws + off);   off += (size_t)N_NODES * 4;
    int*    partials = (int*)(ws + off);   off += 256;
    float2* block_ml = (float2*)(ws + off); off += (size_t)SC_BLOCKS * 8 * sizeof(float2);
    float2* head_ml  = (float2*)(ws + off); off += 64;
    float*  attended = q;  // q is dead after edge_scores; reuse its space
    const int* src = eidx;
    const int* dst = eidx + E_EDGES;

    dim3 blk(256);
    const int gblocks = (N_NODES + TM - 1) / TM;

    gemm128<<<gblocks, blk, 0, stream>>>(x, Wq, bq, nullptr, q, N_NODES);
    gemm128<<<gblocks, blk, 0, stream>>>(x, Wk, bk, nullptr, k, N_NODES);
    gemm128<<<gblocks, blk, 0, stream>>>(x, Wv, bv, nullptr, v, N_NODES);

    // counting sort by dst
    hipMemsetAsync(counts, 0, (size_t)N_NODES * 4, stream);
    hist_kernel<<<1024, blk, 0, stream>>>(dst, counts);
    scan1_kernel<<<NCHUNK, blk, 0, stream>>>(counts, offsets, partials);
    scan2_kernel<<<1, 64, 0, stream>>>(partials);
    scan3_kernel<<<(N_NODES + 255) / 256, blk, 0, stream>>>(offsets, partials, cursor);
    permute_kernel<<<1024, blk, 0, stream>>>(src, dst, cursor, pedge);

    edge_scores<<<SC_BLOCKS, blk, 0, stream>>>(q, k, pedge, scores, block_ml);
    reduce_ml<<<1, blk, 0, stream>>>(block_ml, head_ml, SC_BLOCKS);
    edge_gather<<<(N_NODES + 3) / 4, blk, 0, stream>>>(scores, v, pedge, offsets, head_ml, attended);

    gemm128<<<gblocks, blk, 0, stream>>>(attended, Wo, bo, x, out, N_NODES);
}

// Round 3
// 769.036 us; speedup vs baseline: 1.5936x; 1.1160x over previous
//
#include <hip/hip_runtime.h>
#include <cstdint>
#include <cstddef>

#define N_NODES 100000
#define E_EDGES 1600000
#define HCH 128
#define NHEADS 8
#define HDIM 16

typedef unsigned int uint;

__device__ __forceinline__ unsigned short f2bf(float f) {
    uint u = __float_as_uint(f);
    u = (u + 0x7fff + ((u >> 16) & 1)) >> 16;
    return (unsigned short)u;
}
__device__ __forceinline__ float bflo(uint p) { return __uint_as_float(p << 16); }
__device__ __forceinline__ float bfhi(uint p) { return __uint_as_float(p & 0xffff0000u); }

// dot of 8 bf16 pairs packed in uint4
__device__ __forceinline__ float bfdot8(uint4 a, uint4 b) {
    float s = bflo(a.x) * bflo(b.x) + bfhi(a.x) * bfhi(b.x);
    s += bflo(a.y) * bflo(b.y) + bfhi(a.y) * bfhi(b.y);
    s += bflo(a.z) * bflo(b.z) + bfhi(a.z) * bfhi(b.z);
    s += bflo(a.w) * bflo(b.w) + bfhi(a.w) * bfhi(b.w);
    return s;
}

// ---------------- fused QKV GEMM: fp32 compute, bf16 outputs ----------------
constexpr int TM = 64;
constexpr int QBK = 16;

__global__ __launch_bounds__(256) void gemm_qkv(
    const float* __restrict__ A,
    const float* __restrict__ Wq, const float* __restrict__ Wk, const float* __restrict__ Wv,
    const float* __restrict__ bq, const float* __restrict__ bk, const float* __restrict__ bv,
    unsigned short* __restrict__ qo, unsigned short* __restrict__ ko, unsigned short* __restrict__ vo,
    int M)
{
    __shared__ float As[QBK][TM];        // 4 KB
    __shared__ float Ws[3][QBK][HCH];    // 24 KB
    const int t = threadIdx.x;
    const int m_base = blockIdx.x * TM;
    const int tc = t & 15;
    const int tr = t >> 4;
    const int n0 = tc * 8;
    const int m0 = tr * 4;

    float accq[4][8], acck[4][8], accv[4][8];
#pragma unroll
    for (int i = 0; i < 4; i++)
#pragma unroll
        for (int j = 0; j < 8; j++) { accq[i][j] = 0.f; acck[i][j] = 0.f; accv[i][j] = 0.f; }

    for (int kc = 0; kc < HCH; kc += QBK) {
        // weights: 3 mats x 16 rows x 32 float4 = 1536 float4, 6/thread
#pragma unroll
        for (int i = 0; i < 6; i++) {
            const float* Wm = (i < 2) ? Wq : ((i < 4) ? Wk : Wv);
            int mat = i >> 1;
            int rem = ((i & 1) << 8) + t;     // 0..511
            int kk = rem >> 5;
            int n4 = rem & 31;
            *(float4*)(&Ws[mat][kk][n4 * 4]) =
                *(const float4*)(Wm + (size_t)(kc + kk) * HCH + n4 * 4);
        }
        // A: 64 rows x 16 k = 256 float4, 1/thread, transposed into As
        {
            int r  = t >> 2;
            int kf = t & 3;
            int g  = m_base + r;
            float4 a4 = make_float4(0.f, 0.f, 0.f, 0.f);
            if (g < M) a4 = *(const float4*)(A + (size_t)g * HCH + kc + kf * 4);
            As[kf * 4 + 0][r] = a4.x;
            As[kf * 4 + 1][r] = a4.y;
            As[kf * 4 + 2][r] = a4.z;
            As[kf * 4 + 3][r] = a4.w;
        }
        __syncthreads();
#pragma unroll
        for (int k = 0; k < QBK; k++) {
            float4 a4 = *(const float4*)(&As[k][m0]);
            float av[4] = {a4.x, a4.y, a4.z, a4.w};
            {
                float4 w0 = *(const float4*)(&Ws[0][k][n0]);
                float4 w1 = *(const float4*)(&Ws[0][k][n0 + 4]);
                float wv[8] = {w0.x, w0.y, w0.z, w0.w, w1.x, w1.y, w1.z, w1.w};
#pragma unroll
                for (int i = 0; i < 4; i++)
#pragma unroll
                    for (int j = 0; j < 8; j++) accq[i][j] += av[i] * wv[j];
            }
            {
                float4 w0 = *(const float4*)(&Ws[1][k][n0]);
                float4 w1 = *(const float4*)(&Ws[1][k][n0 + 4]);
                float wv[8] = {w0.x, w0.y, w0.z, w0.w, w1.x, w1.y, w1.z, w1.w};
#pragma unroll
                for (int i = 0; i < 4; i++)
#pragma unroll
                    for (int j = 0; j < 8; j++) acck[i][j] += av[i] * wv[j];
            }
            {
                float4 w0 = *(const float4*)(&Ws[2][k][n0]);
                float4 w1 = *(const float4*)(&Ws[2][k][n0 + 4]);
                float wv[8] = {w0.x, w0.y, w0.z, w0.w, w1.x, w1.y, w1.z, w1.w};
#pragma unroll
                for (int i = 0; i < 4; i++)
#pragma unroll
                    for (int j = 0; j < 8; j++) accv[i][j] += av[i] * wv[j];
            }
        }
        __syncthreads();
    }

    float4 bq0 = *(const float4*)(bq + n0), bq1 = *(const float4*)(bq + n0 + 4);
    float4 bk0 = *(const float4*)(bk + n0), bk1 = *(const float4*)(bk + n0 + 4);
    float4 bv0 = *(const float4*)(bv + n0), bv1 = *(const float4*)(bv + n0 + 4);
#pragma unroll
    for (int i = 0; i < 4; i++) {
        int g = m_base + m0 + i;
        if (g >= M) continue;
        {
            float o[8] = {accq[i][0] + bq0.x, accq[i][1] + bq0.y, accq[i][2] + bq0.z, accq[i][3] + bq0.w,
                          accq[i][4] + bq1.x, accq[i][5] + bq1.y, accq[i][6] + bq1.z, accq[i][7] + bq1.w};
            uint4 p = make_uint4((uint)f2bf(o[0]) | ((uint)f2bf(o[1]) << 16),
                                 (uint)f2bf(o[2]) | ((uint)f2bf(o[3]) << 16),
                                 (uint)f2bf(o[4]) | ((uint)f2bf(o[5]) << 16),
                                 (uint)f2bf(o[6]) | ((uint)f2bf(o[7]) << 16));
            *(uint4*)(qo + (size_t)g * HCH + n0) = p;
        }
        {
            float o[8] = {acck[i][0] + bk0.x, acck[i][1] + bk0.y, acck[i][2] + bk0.z, acck[i][3] + bk0.w,
                          acck[i][4] + bk1.x, acck[i][5] + bk1.y, acck[i][6] + bk1.z, acck[i][7] + bk1.w};
            uint4 p = make_uint4((uint)f2bf(o[0]) | ((uint)f2bf(o[1]) << 16),
                                 (uint)f2bf(o[2]) | ((uint)f2bf(o[3]) << 16),
                                 (uint)f2bf(o[4]) | ((uint)f2bf(o[5]) << 16),
                                 (uint)f2bf(o[6]) | ((uint)f2bf(o[7]) << 16));
            *(uint4*)(ko + (size_t)g * HCH + n0) = p;
        }
        {
            float o[8] = {accv[i][0] + bv0.x, accv[i][1] + bv0.y, accv[i][2] + bv0.z, accv[i][3] + bv0.w,
                          accv[i][4] + bv1.x, accv[i][5] + bv1.y, accv[i][6] + bv1.z, accv[i][7] + bv1.w};
            uint4 p = make_uint4((uint)f2bf(o[0]) | ((uint)f2bf(o[1]) << 16),
                                 (uint)f2bf(o[2]) | ((uint)f2bf(o[3]) << 16),
                                 (uint)f2bf(o[4]) | ((uint)f2bf(o[5]) << 16),
                                 (uint)f2bf(o[6]) | ((uint)f2bf(o[7]) << 16));
            *(uint4*)(vo + (size_t)g * HCH + n0) = p;
        }
    }
}

// ---------------- fp32 GEMM for output: C = A @ W + bias + res ----------------
constexpr int BK = 32;
__global__ __launch_bounds__(256) void gemm128(
    const float* __restrict__ A, const float* __restrict__ W,
    const float* __restrict__ bias, const float* __restrict__ res,
    float* __restrict__ C, int M)
{
    __shared__ float As[BK][TM];
    __shared__ float Ws[BK][HCH];
    const int t = threadIdx.x;
    const int m_base = blockIdx.x * TM;
    const int tc = t & 15;
    const int tr = t >> 4;
    const int n0 = tc * 8;
    const int m0 = tr * 4;

    float acc[4][8];
#pragma unroll
    for (int i = 0; i < 4; i++)
#pragma unroll
        for (int j = 0; j < 8; j++) acc[i][j] = 0.f;

    for (int kc = 0; kc < HCH; kc += BK) {
#pragma unroll
        for (int i = 0; i < 4; i++) {
            int p  = i * 256 + t;
            int kk = p >> 5;
            int n4 = p & 31;
            *(float4*)(&Ws[kk][n4 * 4]) =
                *(const float4*)(W + (size_t)(kc + kk) * HCH + n4 * 4);
        }
#pragma unroll
        for (int i = 0; i < 2; i++) {
            int p  = i * 256 + t;
            int r  = p >> 3;
            int kf = p & 7;
            int g  = m_base + r;
            float4 a4 = make_float4(0.f, 0.f, 0.f, 0.f);
            if (g < M)
                a4 = *(const float4*)(A + (size_t)g * HCH + kc + kf * 4);
            As[kf * 4 + 0][r] = a4.x;
            As[kf * 4 + 1][r] = a4.y;
            As[kf * 4 + 2][r] = a4.z;
            As[kf * 4 + 3][r] = a4.w;
        }
        __syncthreads();
#pragma unroll
        for (int k = 0; k < BK; k++) {
            float4 a4 = *(const float4*)(&As[k][m0]);
            float4 w0 = *(const float4*)(&Ws[k][n0]);
            float4 w1 = *(const float4*)(&Ws[k][n0 + 4]);
            float av[4] = {a4.x, a4.y, a4.z, a4.w};
            float wv[8] = {w0.x, w0.y, w0.z, w0.w, w1.x, w1.y, w1.z, w1.w};
#pragma unroll
            for (int i = 0; i < 4; i++)
#pragma unroll
                for (int j = 0; j < 8; j++) acc[i][j] += av[i] * wv[j];
        }
        __syncthreads();
    }

    float4 b0 = *(const float4*)(bias + n0);
    float4 b1 = *(const float4*)(bias + n0 + 4);
#pragma unroll
    for (int i = 0; i < 4; i++) {
        int g = m_base + m0 + i;
        if (g >= M) continue;
        float o[8] = {acc[i][0] + b0.x, acc[i][1] + b0.y, acc[i][2] + b0.z, acc[i][3] + b0.w,
                      acc[i][4] + b1.x, acc[i][5] + b1.y, acc[i][6] + b1.z, acc[i][7] + b1.w};
        if (res) {
            float4 r0 = *(const float4*)(res + (size_t)g * HCH + n0);
            float4 r1 = *(const float4*)(res + (size_t)g * HCH + n0 + 4);
            o[0] += r0.x; o[1] += r0.y; o[2] += r0.z; o[3] += r0.w;
            o[4] += r1.x; o[5] += r1.y; o[6] += r1.z; o[7] += r1.w;
        }
        *(float4*)(C + (size_t)g * HCH + n0)     = make_float4(o[0], o[1], o[2], o[3]);
        *(float4*)(C + (size_t)g * HCH + n0 + 4) = make_float4(o[4], o[5], o[6], o[7]);
    }
}

// ---------------- counting sort by dst ----------------
constexpr int NCHUNK = (N_NODES + 2047) / 2048;   // 49

__global__ __launch_bounds__(256) void hist_kernel(
    const int* __restrict__ dst, int* __restrict__ counts)
{
    for (int e = blockIdx.x * 256 + threadIdx.x; e < E_EDGES; e += gridDim.x * 256)
        atomicAdd(&counts[dst[e]], 1);
}

__global__ __launch_bounds__(256) void scan1_kernel(
    const int* __restrict__ counts, int* __restrict__ offsets, int* __restrict__ partials)
{
    __shared__ int s[256];
    const int t = threadIdx.x;
    const int base = blockIdx.x * 2048 + t * 8;
    int vals[8];
    int tsum = 0;
#pragma unroll
    for (int j = 0; j < 8; j++) {
        vals[j] = (base + j < N_NODES) ? counts[base + j] : 0;
        tsum += vals[j];
    }
    s[t] = tsum;
    __syncthreads();
    for (int off = 1; off < 256; off <<= 1) {
        int add = (t >= off) ? s[t - off] : 0;
        __syncthreads();
        s[t] += add;
        __syncthreads();
    }
    int run = s[t] - tsum;
    if (t == 255) partials[blockIdx.x] = s[255];
#pragma unroll
    for (int j = 0; j < 8; j++) {
        if (base + j < N_NODES) offsets[base + j] = run;
        run += vals[j];
    }
}

__global__ void scan2_kernel(int* __restrict__ partials)
{
    if (threadIdx.x == 0 && blockIdx.x == 0) {
        int run = 0;
        for (int i = 0; i < NCHUNK; i++) {
            int v = partials[i];
            partials[i] = run;
            run += v;
        }
    }
}

__global__ __launch_bounds__(256) void scan3_kernel(
    int* __restrict__ offsets, const int* __restrict__ partials, int* __restrict__ cursor)
{
    int i = blockIdx.x * 256 + threadIdx.x;
    if (i < N_NODES) {
        int off = offsets[i] + partials[i >> 11];
        offsets[i] = off;
        cursor[i] = off;
    }
    if (i == 0) offsets[N_NODES] = E_EDGES;
}

__global__ __launch_bounds__(256) void permute_kernel(
    const int* __restrict__ src, const int* __restrict__ dst,
    int* __restrict__ cursor, int2* __restrict__ pedge)
{
    for (int e = blockIdx.x * 256 + threadIdx.x; e < E_EDGES; e += gridDim.x * 256) {
        int d = dst[e];
        int pos = atomicAdd(&cursor[d], 1);
        pedge[pos] = make_int2(src[e], d);
    }
}

// ---------------- edge scores (bf16 q/k), unroll-4, online (m,l) ----------------
constexpr int SC_BLOCKS = 1280;
__global__ __launch_bounds__(256) void edge_scores(
    const unsigned short* __restrict__ q, const unsigned short* __restrict__ k,
    const int2* __restrict__ pedge,
    float* __restrict__ scores, float2* __restrict__ block_ml)
{
    const int t = threadIdx.x;
    const int h = t & 7;
    const int step = SC_BLOCKS * 32;          // 40960
    const int e0 = blockIdx.x * 32 + (t >> 3);
    float m = -1e30f, l = 0.f;
    for (int e = e0; e < E_EDGES; e += 4 * step) {
#pragma unroll
        for (int u = 0; u < 4; u++) {
            int ee = e + u * step;
            if (ee >= E_EDGES) break;
            int2 sd = pedge[ee];
            const uint4* qr = (const uint4*)(q + (size_t)sd.y * HCH + h * HDIM);
            const uint4* kr = (const uint4*)(k + (size_t)sd.x * HCH + h * HDIM);
            uint4 qa = qr[0], qb = qr[1];
            uint4 ka = kr[0], kb = kr[1];
            float acc = (bfdot8(qa, ka) + bfdot8(qb, kb)) * 0.25f;
            scores[(size_t)ee * 8 + h] = acc;
            float nm = fmaxf(m, acc);
            l = l * __expf(m - nm) + __expf(acc - nm);
            m = nm;
        }
    }
    __shared__ float sm[256], sl[256];
    sm[t] = m; sl[t] = l;
    __syncthreads();
    if (t < 8) {
        float M = -1e30f, L = 0.f;
        for (int i = t; i < 256; i += 8) {
            float mm = sm[i], ll = sl[i];
            float nm = fmaxf(M, mm);
            L = L * __expf(M - nm) + ll * __expf(mm - nm);
            M = nm;
        }
        block_ml[blockIdx.x * 8 + t] = make_float2(M, L);
    }
}

__global__ __launch_bounds__(256) void reduce_ml(
    const float2* __restrict__ block_ml, float2* __restrict__ head_ml, int nblk)
{
    const int t = threadIdx.x;
    float m = -1e30f, l = 0.f;
    for (int i = t; i < nblk * 8; i += 256) {
        float2 e = block_ml[i];
        float nm = fmaxf(m, e.x);
        l = l * __expf(m - nm) + e.y * __expf(e.x - nm);
        m = nm;
    }
    __shared__ float sm[256], sl[256];
    sm[t] = m; sl[t] = l;
    __syncthreads();
    if (t < 8) {
        float M = -1e30f, L = 0.f;
        for (int i = t; i < 256; i += 8) {
            float mm = sm[i], ll = sl[i];
            float nm = fmaxf(M, mm);
            L = L * __expf(M - nm) + ll * __expf(mm - nm);
            M = nm;
        }
        head_ml[t] = make_float2(M, 1.0f / L);
    }
}

// ---------------- segment reduction, bf16 v, unroll-4 ----------------
__global__ __launch_bounds__(256) void edge_gather(
    const float* __restrict__ scores, const unsigned short* __restrict__ v,
    const int2* __restrict__ pedge, const int* __restrict__ offsets,
    const float2* __restrict__ head_ml, float* __restrict__ attended)
{
    const int t = threadIdx.x;
    const int lane = t & 63;
    const int d = blockIdx.x * 4 + (t >> 6);
    if (d >= N_NODES) return;
    const int h = lane >> 3;
    const float2 ml = head_ml[h];
    const float M = ml.x, invL = ml.y;
    const int start = offsets[d];
    const int end   = offsets[d + 1];
    float a0 = 0.f, a1 = 0.f;
    int i = start;
    for (; i + 3 < end; i += 4) {
        int2 sd0 = pedge[i], sd1 = pedge[i + 1], sd2 = pedge[i + 2], sd3 = pedge[i + 3];
        float s0 = scores[(size_t)(i) * 8 + h];
        float s1 = scores[(size_t)(i + 1) * 8 + h];
        float s2 = scores[(size_t)(i + 2) * 8 + h];
        float s3 = scores[(size_t)(i + 3) * 8 + h];
        uint v0 = *(const uint*)(v + (size_t)sd0.x * HCH + lane * 2);
        uint v1 = *(const uint*)(v + (size_t)sd1.x * HCH + lane * 2);
        uint v2 = *(const uint*)(v + (size_t)sd2.x * HCH + lane * 2);
        uint v3 = *(const uint*)(v + (size_t)sd3.x * HCH + lane * 2);
        float w0 = __expf(s0 - M), w1 = __expf(s1 - M);
        float w2 = __expf(s2 - M), w3 = __expf(s3 - M);
        a0 += w0 * bflo(v0) + w1 * bflo(v1) + w2 * bflo(v2) + w3 * bflo(v3);
        a1 += w0 * bfhi(v0) + w1 * bfhi(v1) + w2 * bfhi(v2) + w3 * bfhi(v3);
    }
    for (; i < end; i++) {
        int2 sd = pedge[i];
        float w = __expf(scores[(size_t)i * 8 + h] - M);
        uint vv = *(const uint*)(v + (size_t)sd.x * HCH + lane * 2);
        a0 += w * bflo(vv);
        a1 += w * bfhi(vv);
    }
    *(float2*)(attended + (size_t)d * HCH + lane * 2) = make_float2(a0 * invL, a1 * invL);
}

extern "C" void kernel_launch(void* const* d_in, const int* in_sizes, int n_in,
                              void* d_out, int out_size, void* d_ws, size_t ws_size,
                              hipStream_t stream)
{
    const float* x  = (const float*)d_in[0];
    const int* eidx = (const int*)d_in[1];
    const float* Wq = (const float*)d_in[2];
    const float* bq = (const float*)d_in[3];
    const float* Wk = (const float*)d_in[4];
    const float* bk = (const float*)d_in[5];
    const float* Wv = (const float*)d_in[6];
    const float* bv = (const float*)d_in[7];
    const float* Wo = (const float*)d_in[8];
    const float* bo = (const float*)d_in[9];
    float* out = (float*)d_out;

    char* ws = (char*)d_ws;
    constexpr size_t SZ_BF   = (size_t)N_NODES * HCH * 2;                // 25.6 MB
    constexpr size_t SZ_F32  = (size_t)N_NODES * HCH * 4;                // 51.2 MB
    constexpr size_t SZ_SC   = (size_t)E_EDGES * NHEADS * 4;             // 51.2 MB
    constexpr size_t SZ_PE   = (size_t)E_EDGES * sizeof(int2);           // 12.8 MB
    size_t off = 0;
    unsigned short* q  = (unsigned short*)(ws + off); off += SZ_BF;
    unsigned short* k  = (unsigned short*)(ws + off); off += SZ_BF;
    unsigned short* v  = (unsigned short*)(ws + off); off += SZ_BF;
    float*  scores     = (float*)(ws + off);  off += SZ_SC;
    float*  attended   = (float*)(ws + off);  off += SZ_F32;
    int2*   pedge      = (int2*)(ws + off);   off += SZ_PE;
    int*    offsets    = (int*)(ws + off);    off += ((size_t)N_NODES + 1) * 4 + 4;
    int*    cursor     = (int*)(ws + off);    off += (size_t)N_NODES * 4;
    int*    counts     = (int*)(ws + off);    off += (size_t)N_NODES * 4;
    int*    partials   = (int*)(ws + off);    off += 256;
    float2* block_ml   = (float2*)(ws + off); off += (size_t)SC_BLOCKS * 8 * sizeof(float2);
    float2* head_ml    = (float2*)(ws + off); off += 64;
    const int* src = eidx;
    const int* dst = eidx + E_EDGES;

    dim3 blk(256);
    const int gblocks = (N_NODES + TM - 1) / TM;

    gemm_qkv<<<gblocks, blk, 0, stream>>>(x, Wq, Wk, Wv, bq, bk, bv, q, k, v, N_NODES);

    hipMemsetAsync(counts, 0, (size_t)N_NODES * 4, stream);
    hist_kernel<<<1024, blk, 0, stream>>>(dst, counts);
    scan1_kernel<<<NCHUNK, blk, 0, stream>>>(counts, offsets, partials);
    scan2_kernel<<<1, 64, 0, stream>>>(partials);
    scan3_kernel<<<(N_NODES + 255) / 256, blk, 0, stream>>>(offsets, partials, cursor);
    permute_kernel<<<1024, blk, 0, stream>>>(src, dst, cursor, pedge);

    edge_scores<<<SC_BLOCKS, blk, 0, stream>>>(q, k, pedge, scores, block_ml);
    reduce_ml<<<1, blk, 0, stream>>>(block_ml, head_ml, SC_BLOCKS);
    edge_gather<<<(N_NODES + 3) / 4, blk, 0, stream>>>(scores, v, pedge, offsets, head_ml, attended);

    gemm128<<<gblocks, blk, 0, stream>>>(attended, Wo, bo, x, out, N_NODES);
}

// Round 4
// 519.381 us; speedup vs baseline: 2.3595x; 1.4807x over previous
//
#include <hip/hip_runtime.h>
#include <cstdint>
#include <cstddef>

#define N_NODES 100000
#define E_EDGES 1600000
#define HCH 128
#define NHEADS 8
#define HDIM 16

typedef unsigned int uint;
typedef __attribute__((ext_vector_type(8))) short short8;
typedef __attribute__((ext_vector_type(4))) float floatx4;

__device__ __forceinline__ unsigned short f2bf(float f) {
    uint u = __float_as_uint(f);
    u = (u + 0x7fff + ((u >> 16) & 1)) >> 16;
    return (unsigned short)u;
}
__device__ __forceinline__ float bflo(uint p) { return __uint_as_float(p << 16); }
__device__ __forceinline__ float bfhi(uint p) { return __uint_as_float(p & 0xffff0000u); }

__device__ __forceinline__ float bfdot8(uint4 a, uint4 b) {
    float s = bflo(a.x) * bflo(b.x) + bfhi(a.x) * bfhi(b.x);
    s += bflo(a.y) * bflo(b.y) + bfhi(a.y) * bfhi(b.y);
    s += bflo(a.z) * bflo(b.z) + bfhi(a.z) * bfhi(b.z);
    s += bflo(a.w) * bflo(b.w) + bfhi(a.w) * bfhi(b.w);
    return s;
}

// LDS geometry shared by both MFMA GEMMs
// As: 64 x (128+8) bf16 = 17408 B ; Wt: 128 x (128+8) bf16 = 34816 B
// Cs (epilogue) aliases Wt: 64 x 132 fp32 = 33792 B
#define LDSPAD 8
#define SMEM_BYTES (17408 + 34816)

// ---------------- MFMA QKV GEMM: q/k/v = bf16(x @ W + b), grid (mblocks, 3) ---
__global__ __launch_bounds__(256) void gemm_qkv(
    const float* __restrict__ A,
    const float* __restrict__ Wq, const float* __restrict__ Wk, const float* __restrict__ Wv,
    const float* __restrict__ bq, const float* __restrict__ bk, const float* __restrict__ bv,
    unsigned short* __restrict__ qo, unsigned short* __restrict__ ko, unsigned short* __restrict__ vo,
    int M)
{
    __shared__ __align__(16) char smem[SMEM_BYTES];
    unsigned short (*As)[HCH + LDSPAD] = (unsigned short(*)[HCH + LDSPAD])smem;
    unsigned short (*Wt)[HCH + LDSPAD] = (unsigned short(*)[HCH + LDSPAD])(smem + 17408);
    float (*Cs)[132] = (float(*)[132])(smem + 17408);

    const int t = threadIdx.x;
    const int mb = blockIdx.x * 64;
    const float* W;
    const float* bias;
    unsigned short* out;
    if (blockIdx.y == 0)      { W = Wq; bias = bq; out = qo; }
    else if (blockIdx.y == 1) { W = Wk; bias = bk; out = ko; }
    else                      { W = Wv; bias = bv; out = vo; }

    // stage A (64x128 fp32 -> bf16), 2048 float4 units
#pragma unroll
    for (int i = 0; i < 8; i++) {
        int p = t + i * 256;
        int row = p >> 5, c4 = p & 31;
        int g = mb + row;
        float4 a4 = make_float4(0.f, 0.f, 0.f, 0.f);
        if (g < M) a4 = *(const float4*)(A + (size_t)g * HCH + c4 * 4);
        uint lo = (uint)f2bf(a4.x) | ((uint)f2bf(a4.y) << 16);
        uint hi = (uint)f2bf(a4.z) | ((uint)f2bf(a4.w) << 16);
        *(uint2*)(&As[row][c4 * 4]) = make_uint2(lo, hi);
    }
    // stage W transposed: Wt[n][k], column reads (coalesced across n)
#pragma unroll
    for (int i = 0; i < 16; i++) {
        int p = t + i * 256;        // 4096 units of 4 k-elements
        int n = p & 127, k4 = p >> 7;
        float w0 = W[(size_t)(k4 * 4 + 0) * HCH + n];
        float w1 = W[(size_t)(k4 * 4 + 1) * HCH + n];
        float w2 = W[(size_t)(k4 * 4 + 2) * HCH + n];
        float w3 = W[(size_t)(k4 * 4 + 3) * HCH + n];
        uint lo = (uint)f2bf(w0) | ((uint)f2bf(w1) << 16);
        uint hi = (uint)f2bf(w2) | ((uint)f2bf(w3) << 16);
        *(uint2*)(&Wt[n][k4 * 4]) = make_uint2(lo, hi);
    }
    __syncthreads();

    const int lane = t & 63;
    const int w = t >> 6;
    const int m_l = lane & 15;
    const int q_l = lane >> 4;

    floatx4 acc[8];
#pragma unroll
    for (int tl = 0; tl < 8; tl++) acc[tl] = (floatx4){0.f, 0.f, 0.f, 0.f};

#pragma unroll
    for (int ks = 0; ks < HCH; ks += 32) {
        short8 af = *(const short8*)(&As[w * 16 + m_l][ks + q_l * 8]);
#pragma unroll
        for (int tl = 0; tl < 8; tl++) {
            short8 bf = *(const short8*)(&Wt[tl * 16 + m_l][ks + q_l * 8]);
            acc[tl] = __builtin_amdgcn_mfma_f32_16x16x32_bf16(af, bf, acc[tl], 0, 0, 0);
        }
    }
    __syncthreads();   // Wt reads done before Cs overwrites

#pragma unroll
    for (int tl = 0; tl < 8; tl++)
#pragma unroll
        for (int r = 0; r < 4; r++)
            Cs[w * 16 + q_l * 4 + r][tl * 16 + m_l] = acc[tl][r];
    __syncthreads();

    // coalesced bf16 store + bias
#pragma unroll
    for (int i = 0; i < 8; i++) {
        int p = t + i * 256;
        int row = p >> 5, c4 = p & 31;
        int g = mb + row;
        if (g >= M) continue;
        float4 b4 = *(const float4*)(bias + c4 * 4);
        float v0 = Cs[row][c4 * 4 + 0] + b4.x;
        float v1 = Cs[row][c4 * 4 + 1] + b4.y;
        float v2 = Cs[row][c4 * 4 + 2] + b4.z;
        float v3 = Cs[row][c4 * 4 + 3] + b4.w;
        uint lo = (uint)f2bf(v0) | ((uint)f2bf(v1) << 16);
        uint hi = (uint)f2bf(v2) | ((uint)f2bf(v3) << 16);
        *(uint2*)(out + (size_t)g * HCH + c4 * 4) = make_uint2(lo, hi);
    }
}

// ---------------- MFMA output GEMM: out = x + bf16(attended) @ Wo + bo -------
__global__ __launch_bounds__(256) void gemm_out(
    const float* __restrict__ A, const float* __restrict__ W,
    const float* __restrict__ bias, const float* __restrict__ res,
    float* __restrict__ C, int M)
{
    __shared__ __align__(16) char smem[SMEM_BYTES];
    unsigned short (*As)[HCH + LDSPAD] = (unsigned short(*)[HCH + LDSPAD])smem;
    unsigned short (*Wt)[HCH + LDSPAD] = (unsigned short(*)[HCH + LDSPAD])(smem + 17408);
    float (*Cs)[132] = (float(*)[132])(smem + 17408);

    const int t = threadIdx.x;
    const int mb = blockIdx.x * 64;

#pragma unroll
    for (int i = 0; i < 8; i++) {
        int p = t + i * 256;
        int row = p >> 5, c4 = p & 31;
        int g = mb + row;
        float4 a4 = make_float4(0.f, 0.f, 0.f, 0.f);
        if (g < M) a4 = *(const float4*)(A + (size_t)g * HCH + c4 * 4);
        uint lo = (uint)f2bf(a4.x) | ((uint)f2bf(a4.y) << 16);
        uint hi = (uint)f2bf(a4.z) | ((uint)f2bf(a4.w) << 16);
        *(uint2*)(&As[row][c4 * 4]) = make_uint2(lo, hi);
    }
#pragma unroll
    for (int i = 0; i < 16; i++) {
        int p = t + i * 256;
        int n = p & 127, k4 = p >> 7;
        float w0 = W[(size_t)(k4 * 4 + 0) * HCH + n];
        float w1 = W[(size_t)(k4 * 4 + 1) * HCH + n];
        float w2 = W[(size_t)(k4 * 4 + 2) * HCH + n];
        float w3 = W[(size_t)(k4 * 4 + 3) * HCH + n];
        uint lo = (uint)f2bf(w0) | ((uint)f2bf(w1) << 16);
        uint hi = (uint)f2bf(w2) | ((uint)f2bf(w3) << 16);
        *(uint2*)(&Wt[n][k4 * 4]) = make_uint2(lo, hi);
    }
    __syncthreads();

    const int lane = t & 63;
    const int w = t >> 6;
    const int m_l = lane & 15;
    const int q_l = lane >> 4;

    floatx4 acc[8];
#pragma unroll
    for (int tl = 0; tl < 8; tl++) acc[tl] = (floatx4){0.f, 0.f, 0.f, 0.f};

#pragma unroll
    for (int ks = 0; ks < HCH; ks += 32) {
        short8 af = *(const short8*)(&As[w * 16 + m_l][ks + q_l * 8]);
#pragma unroll
        for (int tl = 0; tl < 8; tl++) {
            short8 bf = *(const short8*)(&Wt[tl * 16 + m_l][ks + q_l * 8]);
            acc[tl] = __builtin_amdgcn_mfma_f32_16x16x32_bf16(af, bf, acc[tl], 0, 0, 0);
        }
    }
    __syncthreads();

#pragma unroll
    for (int tl = 0; tl < 8; tl++)
#pragma unroll
        for (int r = 0; r < 4; r++)
            Cs[w * 16 + q_l * 4 + r][tl * 16 + m_l] = acc[tl][r];
    __syncthreads();

#pragma unroll
    for (int i = 0; i < 8; i++) {
        int p = t + i * 256;
        int row = p >> 5, c4 = p & 31;
        int g = mb + row;
        if (g >= M) continue;
        float4 b4 = *(const float4*)(bias + c4 * 4);
        float4 r4 = *(const float4*)(res + (size_t)g * HCH + c4 * 4);
        float4 o;
        o.x = Cs[row][c4 * 4 + 0] + b4.x + r4.x;
        o.y = Cs[row][c4 * 4 + 1] + b4.y + r4.y;
        o.z = Cs[row][c4 * 4 + 2] + b4.z + r4.z;
        o.w = Cs[row][c4 * 4 + 3] + b4.w + r4.w;
        *(float4*)(C + (size_t)g * HCH + c4 * 4) = o;
    }
}

// ---------------- counting sort by dst ----------------
constexpr int NCHUNK = (N_NODES + 2047) / 2048;   // 49

__global__ __launch_bounds__(256) void hist_kernel(
    const int* __restrict__ dst, int* __restrict__ counts)
{
    for (int e = blockIdx.x * 256 + threadIdx.x; e < E_EDGES; e += gridDim.x * 256)
        atomicAdd(&counts[dst[e]], 1);
}

__global__ __launch_bounds__(256) void scan1_kernel(
    const int* __restrict__ counts, int* __restrict__ offsets, int* __restrict__ partials)
{
    __shared__ int s[256];
    const int t = threadIdx.x;
    const int base = blockIdx.x * 2048 + t * 8;
    int vals[8];
    int tsum = 0;
#pragma unroll
    for (int j = 0; j < 8; j++) {
        vals[j] = (base + j < N_NODES) ? counts[base + j] : 0;
        tsum += vals[j];
    }
    s[t] = tsum;
    __syncthreads();
    for (int off = 1; off < 256; off <<= 1) {
        int add = (t >= off) ? s[t - off] : 0;
        __syncthreads();
        s[t] += add;
        __syncthreads();
    }
    int run = s[t] - tsum;
    if (t == 255) partials[blockIdx.x] = s[255];
#pragma unroll
    for (int j = 0; j < 8; j++) {
        if (base + j < N_NODES) offsets[base + j] = run;
        run += vals[j];
    }
}

__global__ void scan2_kernel(int* __restrict__ partials)
{
    if (threadIdx.x == 0 && blockIdx.x == 0) {
        int run = 0;
        for (int i = 0; i < NCHUNK; i++) {
            int v = partials[i];
            partials[i] = run;
            run += v;
        }
    }
}

__global__ __launch_bounds__(256) void scan3_kernel(
    int* __restrict__ offsets, const int* __restrict__ partials, int* __restrict__ cursor)
{
    int i = blockIdx.x * 256 + threadIdx.x;
    if (i < N_NODES) {
        int off = offsets[i] + partials[i >> 11];
        offsets[i] = off;
        cursor[i] = off;
    }
    if (i == 0) offsets[N_NODES] = E_EDGES;
}

__global__ __launch_bounds__(256) void permute_kernel(
    const int* __restrict__ src, const int* __restrict__ dst,
    int* __restrict__ cursor, int2* __restrict__ pedge)
{
    for (int e = blockIdx.x * 256 + threadIdx.x; e < E_EDGES; e += gridDim.x * 256) {
        int d = dst[e];
        int pos = atomicAdd(&cursor[d], 1);
        pedge[pos] = make_int2(src[e], d);
    }
}

// ---------------- edge scores (bf16 q/k), unroll-4, online (m,l) ----------------
constexpr int SC_BLOCKS = 1280;
__global__ __launch_bounds__(256) void edge_scores(
    const unsigned short* __restrict__ q, const unsigned short* __restrict__ k,
    const int2* __restrict__ pedge,
    float* __restrict__ scores, float2* __restrict__ block_ml)
{
    const int t = threadIdx.x;
    const int h = t & 7;
    const int step = SC_BLOCKS * 32;
    const int e0 = blockIdx.x * 32 + (t >> 3);
    float m = -1e30f, l = 0.f;
    for (int e = e0; e < E_EDGES; e += 4 * step) {
#pragma unroll
        for (int u = 0; u < 4; u++) {
            int ee = e + u * step;
            if (ee >= E_EDGES) break;
            int2 sd = pedge[ee];
            const uint4* qr = (const uint4*)(q + (size_t)sd.y * HCH + h * HDIM);
            const uint4* kr = (const uint4*)(k + (size_t)sd.x * HCH + h * HDIM);
            uint4 qa = qr[0], qb = qr[1];
            uint4 ka = kr[0], kb = kr[1];
            float acc = (bfdot8(qa, ka) + bfdot8(qb, kb)) * 0.25f;
            scores[(size_t)ee * 8 + h] = acc;
            float nm = fmaxf(m, acc);
            l = l * __expf(m - nm) + __expf(acc - nm);
            m = nm;
        }
    }
    __shared__ float sm[256], sl[256];
    sm[t] = m; sl[t] = l;
    __syncthreads();
    if (t < 8) {
        float M = -1e30f, L = 0.f;
        for (int i = t; i < 256; i += 8) {
            float mm = sm[i], ll = sl[i];
            float nm = fmaxf(M, mm);
            L = L * __expf(M - nm) + ll * __expf(mm - nm);
            M = nm;
        }
        block_ml[blockIdx.x * 8 + t] = make_float2(M, L);
    }
}

__global__ __launch_bounds__(256) void reduce_ml(
    const float2* __restrict__ block_ml, float2* __restrict__ head_ml, int nblk)
{
    const int t = threadIdx.x;
    float m = -1e30f, l = 0.f;
    for (int i = t; i < nblk * 8; i += 256) {
        float2 e = block_ml[i];
        float nm = fmaxf(m, e.x);
        l = l * __expf(m - nm) + e.y * __expf(e.x - nm);
        m = nm;
    }
    __shared__ float sm[256], sl[256];
    sm[t] = m; sl[t] = l;
    __syncthreads();
    if (t < 8) {
        float M = -1e30f, L = 0.f;
        for (int i = t; i < 256; i += 8) {
            float mm = sm[i], ll = sl[i];
            float nm = fmaxf(M, mm);
            L = L * __expf(M - nm) + ll * __expf(mm - nm);
            M = nm;
        }
        head_ml[t] = make_float2(M, 1.0f / L);
    }
}

// ---------------- segment reduction, bf16 v, unroll-4 ----------------
__global__ __launch_bounds__(256) void edge_gather(
    const float* __restrict__ scores, const unsigned short* __restrict__ v,
    const int2* __restrict__ pedge, const int* __restrict__ offsets,
    const float2* __restrict__ head_ml, float* __restrict__ attended)
{
    const int t = threadIdx.x;
    const int lane = t & 63;
    const int d = blockIdx.x * 4 + (t >> 6);
    if (d >= N_NODES) return;
    const int h = lane >> 3;
    const float2 ml = head_ml[h];
    const float M = ml.x, invL = ml.y;
    const int start = offsets[d];
    const int end   = offsets[d + 1];
    float a0 = 0.f, a1 = 0.f;
    int i = start;
    for (; i + 3 < end; i += 4) {
        int2 sd0 = pedge[i], sd1 = pedge[i + 1], sd2 = pedge[i + 2], sd3 = pedge[i + 3];
        float s0 = scores[(size_t)(i) * 8 + h];
        float s1 = scores[(size_t)(i + 1) * 8 + h];
        float s2 = scores[(size_t)(i + 2) * 8 + h];
        float s3 = scores[(size_t)(i + 3) * 8 + h];
        uint v0 = *(const uint*)(v + (size_t)sd0.x * HCH + lane * 2);
        uint v1 = *(const uint*)(v + (size_t)sd1.x * HCH + lane * 2);
        uint v2 = *(const uint*)(v + (size_t)sd2.x * HCH + lane * 2);
        uint v3 = *(const uint*)(v + (size_t)sd3.x * HCH + lane * 2);
        float w0 = __expf(s0 - M), w1 = __expf(s1 - M);
        float w2 = __expf(s2 - M), w3 = __expf(s3 - M);
        a0 += w0 * bflo(v0) + w1 * bflo(v1) + w2 * bflo(v2) + w3 * bflo(v3);
        a1 += w0 * bfhi(v0) + w1 * bfhi(v1) + w2 * bfhi(v2) + w3 * bfhi(v3);
    }
    for (; i < end; i++) {
        int2 sd = pedge[i];
        float w = __expf(scores[(size_t)i * 8 + h] - M);
        uint vv = *(const uint*)(v + (size_t)sd.x * HCH + lane * 2);
        a0 += w * bflo(vv);
        a1 += w * bfhi(vv);
    }
    *(float2*)(attended + (size_t)d * HCH + lane * 2) = make_float2(a0 * invL, a1 * invL);
}

extern "C" void kernel_launch(void* const* d_in, const int* in_sizes, int n_in,
                              void* d_out, int out_size, void* d_ws, size_t ws_size,
                              hipStream_t stream)
{
    const float* x  = (const float*)d_in[0];
    const int* eidx = (const int*)d_in[1];
    const float* Wq = (const float*)d_in[2];
    const float* bq = (const float*)d_in[3];
    const float* Wk = (const float*)d_in[4];
    const float* bk = (const float*)d_in[5];
    const float* Wv = (const float*)d_in[6];
    const float* bv = (const float*)d_in[7];
    const float* Wo = (const float*)d_in[8];
    const float* bo = (const float*)d_in[9];
    float* out = (float*)d_out;

    char* ws = (char*)d_ws;
    constexpr size_t SZ_BF   = (size_t)N_NODES * HCH * 2;
    constexpr size_t SZ_F32  = (size_t)N_NODES * HCH * 4;
    constexpr size_t SZ_SC   = (size_t)E_EDGES * NHEADS * 4;
    constexpr size_t SZ_PE   = (size_t)E_EDGES * sizeof(int2);
    size_t off = 0;
    unsigned short* q  = (unsigned short*)(ws + off); off += SZ_BF;
    unsigned short* k  = (unsigned short*)(ws + off); off += SZ_BF;
    unsigned short* v  = (unsigned short*)(ws + off); off += SZ_BF;
    float*  scores     = (float*)(ws + off);  off += SZ_SC;
    float*  attended   = (float*)(ws + off);  off += SZ_F32;
    int2*   pedge      = (int2*)(ws + off);   off += SZ_PE;
    int*    offsets    = (int*)(ws + off);    off += ((size_t)N_NODES + 1) * 4 + 4;
    int*    cursor     = (int*)(ws + off);    off += (size_t)N_NODES * 4;
    int*    counts     = (int*)(ws + off);    off += (size_t)N_NODES * 4;
    int*    partials   = (int*)(ws + off);    off += 256;
    float2* block_ml   = (float2*)(ws + off); off += (size_t)SC_BLOCKS * 8 * sizeof(float2);
    float2* head_ml    = (float2*)(ws + off); off += 64;
    const int* src = eidx;
    const int* dst = eidx + E_EDGES;

    dim3 blk(256);
    const int gblocks = (N_NODES + 63) / 64;

    gemm_qkv<<<dim3(gblocks, 3), blk, 0, stream>>>(x, Wq, Wk, Wv, bq, bk, bv, q, k, v, N_NODES);

    hipMemsetAsync(counts, 0, (size_t)N_NODES * 4, stream);
    hist_kernel<<<1024, blk, 0, stream>>>(dst, counts);
    scan1_kernel<<<NCHUNK, blk, 0, stream>>>(counts, offsets, partials);
    scan2_kernel<<<1, 64, 0, stream>>>(partials);
    scan3_kernel<<<(N_NODES + 255) / 256, blk, 0, stream>>>(offsets, partials, cursor);
    permute_kernel<<<1024, blk, 0, stream>>>(src, dst, cursor, pedge);

    edge_scores<<<SC_BLOCKS, blk, 0, stream>>>(q, k, pedge, scores, block_ml);
    reduce_ml<<<1, blk, 0, stream>>>(block_ml, head_ml, SC_BLOCKS);
    edge_gather<<<(N_NODES + 3) / 4, blk, 0, stream>>>(scores, v, pedge, offsets, head_ml, attended);

    gemm_out<<<gblocks, blk, 0, stream>>>(attended, Wo, bo, x, out, N_NODES);
}

// Round 5
// 424.501 us; speedup vs baseline: 2.8869x; 1.2235x over previous
//
#include <hip/hip_runtime.h>
#include <cstdint>
#include <cstddef>

#define N_NODES 100000
#define E_EDGES 1600000
#define HCH 128
#define NHEADS 8
#define HDIM 16

typedef unsigned int uint;
typedef __attribute__((ext_vector_type(8))) short short8;
typedef __attribute__((ext_vector_type(4))) float floatx4;

__device__ __forceinline__ unsigned short f2bf(float f) {
    uint u = __float_as_uint(f);
    u = (u + 0x7fff + ((u >> 16) & 1)) >> 16;
    return (unsigned short)u;
}
__device__ __forceinline__ float bflo(uint p) { return __uint_as_float(p << 16); }
__device__ __forceinline__ float bfhi(uint p) { return __uint_as_float(p & 0xffff0000u); }

__device__ __forceinline__ float bfdot8(uint4 a, uint4 b) {
    float s = bflo(a.x) * bflo(b.x) + bfhi(a.x) * bfhi(b.x);
    s += bflo(a.y) * bflo(b.y) + bfhi(a.y) * bfhi(b.y);
    s += bflo(a.z) * bflo(b.z) + bfhi(a.z) * bfhi(b.z);
    s += bflo(a.w) * bflo(b.w) + bfhi(a.w) * bfhi(b.w);
    return s;
}

// ================= MFMA GEMMs (unchanged from R4) =================
#define LDSPAD 8
#define SMEM_BYTES (17408 + 34816)

__global__ __launch_bounds__(256) void gemm_qkv(
    const float* __restrict__ A,
    const float* __restrict__ Wq, const float* __restrict__ Wk, const float* __restrict__ Wv,
    const float* __restrict__ bq, const float* __restrict__ bk, const float* __restrict__ bv,
    unsigned short* __restrict__ qo, unsigned short* __restrict__ ko, unsigned short* __restrict__ vo,
    int M)
{
    __shared__ __align__(16) char smem[SMEM_BYTES];
    unsigned short (*As)[HCH + LDSPAD] = (unsigned short(*)[HCH + LDSPAD])smem;
    unsigned short (*Wt)[HCH + LDSPAD] = (unsigned short(*)[HCH + LDSPAD])(smem + 17408);
    float (*Cs)[132] = (float(*)[132])(smem + 17408);

    const int t = threadIdx.x;
    const int mb = blockIdx.x * 64;
    const float* W;
    const float* bias;
    unsigned short* out;
    if (blockIdx.y == 0)      { W = Wq; bias = bq; out = qo; }
    else if (blockIdx.y == 1) { W = Wk; bias = bk; out = ko; }
    else                      { W = Wv; bias = bv; out = vo; }

#pragma unroll
    for (int i = 0; i < 8; i++) {
        int p = t + i * 256;
        int row = p >> 5, c4 = p & 31;
        int g = mb + row;
        float4 a4 = make_float4(0.f, 0.f, 0.f, 0.f);
        if (g < M) a4 = *(const float4*)(A + (size_t)g * HCH + c4 * 4);
        uint lo = (uint)f2bf(a4.x) | ((uint)f2bf(a4.y) << 16);
        uint hi = (uint)f2bf(a4.z) | ((uint)f2bf(a4.w) << 16);
        *(uint2*)(&As[row][c4 * 4]) = make_uint2(lo, hi);
    }
#pragma unroll
    for (int i = 0; i < 16; i++) {
        int p = t + i * 256;
        int n = p & 127, k4 = p >> 7;
        float w0 = W[(size_t)(k4 * 4 + 0) * HCH + n];
        float w1 = W[(size_t)(k4 * 4 + 1) * HCH + n];
        float w2 = W[(size_t)(k4 * 4 + 2) * HCH + n];
        float w3 = W[(size_t)(k4 * 4 + 3) * HCH + n];
        uint lo = (uint)f2bf(w0) | ((uint)f2bf(w1) << 16);
        uint hi = (uint)f2bf(w2) | ((uint)f2bf(w3) << 16);
        *(uint2*)(&Wt[n][k4 * 4]) = make_uint2(lo, hi);
    }
    __syncthreads();

    const int lane = t & 63;
    const int w = t >> 6;
    const int m_l = lane & 15;
    const int q_l = lane >> 4;

    floatx4 acc[8];
#pragma unroll
    for (int tl = 0; tl < 8; tl++) acc[tl] = (floatx4){0.f, 0.f, 0.f, 0.f};

#pragma unroll
    for (int ks = 0; ks < HCH; ks += 32) {
        short8 af = *(const short8*)(&As[w * 16 + m_l][ks + q_l * 8]);
#pragma unroll
        for (int tl = 0; tl < 8; tl++) {
            short8 bf = *(const short8*)(&Wt[tl * 16 + m_l][ks + q_l * 8]);
            acc[tl] = __builtin_amdgcn_mfma_f32_16x16x32_bf16(af, bf, acc[tl], 0, 0, 0);
        }
    }
    __syncthreads();

#pragma unroll
    for (int tl = 0; tl < 8; tl++)
#pragma unroll
        for (int r = 0; r < 4; r++)
            Cs[w * 16 + q_l * 4 + r][tl * 16 + m_l] = acc[tl][r];
    __syncthreads();

#pragma unroll
    for (int i = 0; i < 8; i++) {
        int p = t + i * 256;
        int row = p >> 5, c4 = p & 31;
        int g = mb + row;
        if (g >= M) continue;
        float4 b4 = *(const float4*)(bias + c4 * 4);
        float v0 = Cs[row][c4 * 4 + 0] + b4.x;
        float v1 = Cs[row][c4 * 4 + 1] + b4.y;
        float v2 = Cs[row][c4 * 4 + 2] + b4.z;
        float v3 = Cs[row][c4 * 4 + 3] + b4.w;
        uint lo = (uint)f2bf(v0) | ((uint)f2bf(v1) << 16);
        uint hi = (uint)f2bf(v2) | ((uint)f2bf(v3) << 16);
        *(uint2*)(out + (size_t)g * HCH + c4 * 4) = make_uint2(lo, hi);
    }
}

__global__ __launch_bounds__(256) void gemm_out(
    const float* __restrict__ A, const float* __restrict__ W,
    const float* __restrict__ bias, const float* __restrict__ res,
    float* __restrict__ C, int M)
{
    __shared__ __align__(16) char smem[SMEM_BYTES];
    unsigned short (*As)[HCH + LDSPAD] = (unsigned short(*)[HCH + LDSPAD])smem;
    unsigned short (*Wt)[HCH + LDSPAD] = (unsigned short(*)[HCH + LDSPAD])(smem + 17408);
    float (*Cs)[132] = (float(*)[132])(smem + 17408);

    const int t = threadIdx.x;
    const int mb = blockIdx.x * 64;

#pragma unroll
    for (int i = 0; i < 8; i++) {
        int p = t + i * 256;
        int row = p >> 5, c4 = p & 31;
        int g = mb + row;
        float4 a4 = make_float4(0.f, 0.f, 0.f, 0.f);
        if (g < M) a4 = *(const float4*)(A + (size_t)g * HCH + c4 * 4);
        uint lo = (uint)f2bf(a4.x) | ((uint)f2bf(a4.y) << 16);
        uint hi = (uint)f2bf(a4.z) | ((uint)f2bf(a4.w) << 16);
        *(uint2*)(&As[row][c4 * 4]) = make_uint2(lo, hi);
    }
#pragma unroll
    for (int i = 0; i < 16; i++) {
        int p = t + i * 256;
        int n = p & 127, k4 = p >> 7;
        float w0 = W[(size_t)(k4 * 4 + 0) * HCH + n];
        float w1 = W[(size_t)(k4 * 4 + 1) * HCH + n];
        float w2 = W[(size_t)(k4 * 4 + 2) * HCH + n];
        float w3 = W[(size_t)(k4 * 4 + 3) * HCH + n];
        uint lo = (uint)f2bf(w0) | ((uint)f2bf(w1) << 16);
        uint hi = (uint)f2bf(w2) | ((uint)f2bf(w3) << 16);
        *(uint2*)(&Wt[n][k4 * 4]) = make_uint2(lo, hi);
    }
    __syncthreads();

    const int lane = t & 63;
    const int w = t >> 6;
    const int m_l = lane & 15;
    const int q_l = lane >> 4;

    floatx4 acc[8];
#pragma unroll
    for (int tl = 0; tl < 8; tl++) acc[tl] = (floatx4){0.f, 0.f, 0.f, 0.f};

#pragma unroll
    for (int ks = 0; ks < HCH; ks += 32) {
        short8 af = *(const short8*)(&As[w * 16 + m_l][ks + q_l * 8]);
#pragma unroll
        for (int tl = 0; tl < 8; tl++) {
            short8 bf = *(const short8*)(&Wt[tl * 16 + m_l][ks + q_l * 8]);
            acc[tl] = __builtin_amdgcn_mfma_f32_16x16x32_bf16(af, bf, acc[tl], 0, 0, 0);
        }
    }
    __syncthreads();

#pragma unroll
    for (int tl = 0; tl < 8; tl++)
#pragma unroll
        for (int r = 0; r < 4; r++)
            Cs[w * 16 + q_l * 4 + r][tl * 16 + m_l] = acc[tl][r];
    __syncthreads();

#pragma unroll
    for (int i = 0; i < 8; i++) {
        int p = t + i * 256;
        int row = p >> 5, c4 = p & 31;
        int g = mb + row;
        if (g >= M) continue;
        float4 b4 = *(const float4*)(bias + c4 * 4);
        float4 r4 = *(const float4*)(res + (size_t)g * HCH + c4 * 4);
        float4 o;
        o.x = Cs[row][c4 * 4 + 0] + b4.x + r4.x;
        o.y = Cs[row][c4 * 4 + 1] + b4.y + r4.y;
        o.z = Cs[row][c4 * 4 + 2] + b4.z + r4.z;
        o.w = Cs[row][c4 * 4 + 3] + b4.w + r4.w;
        *(float4*)(C + (size_t)g * HCH + c4 * 4) = o;
    }
}

// ================= two-pass bucketed counting sort by dst =================
constexpr int BSHIFT = 8;                               // bucket = dst >> 8 (256 nodes/bucket)
constexpr int NBUCK  = ((N_NODES - 1) >> BSHIFT) + 1;   // 391
constexpr int S1_GRID = 256;
constexpr int S1_CH   = (E_EDGES + S1_GRID - 1) / S1_GRID;  // 6250
constexpr int S2_CAP  = 6144;                           // LDS edge stage cap (mean 4096, sd 64)

// global bucket totals
__global__ __launch_bounds__(256) void bucket_hist(
    const int* __restrict__ dst, int* __restrict__ bucket_total)
{
    __shared__ int cnt[NBUCK];
    const int t = threadIdx.x;
    for (int b = t; b < NBUCK; b += 256) cnt[b] = 0;
    __syncthreads();
    const int e0 = blockIdx.x * S1_CH;
    const int n = min(S1_CH, E_EDGES - e0);
    for (int i = t; i < n; i += 256)
        atomicAdd(&cnt[dst[e0 + i] >> BSHIFT], 1);
    __syncthreads();
    for (int b = t; b < NBUCK; b += 256)
        if (cnt[b]) atomicAdd(&bucket_total[b], cnt[b]);
}

// exclusive scan of bucket totals -> bucket_start[0..NBUCK], init cursors
__global__ __launch_bounds__(512) void bucket_scan(
    const int* __restrict__ bucket_total, int* __restrict__ bucket_start,
    int* __restrict__ bucket_cursor, int* __restrict__ offsets)
{
    __shared__ int s[512];
    const int t = threadIdx.x;
    int v = (t < NBUCK) ? bucket_total[t] : 0;
    s[t] = v;
    __syncthreads();
    for (int off = 1; off < 512; off <<= 1) {
        int a = (t >= off) ? s[t - off] : 0;
        __syncthreads();
        s[t] += a;
        __syncthreads();
    }
    int excl = s[t] - v;
    if (t < NBUCK) { bucket_start[t] = excl; bucket_cursor[t] = excl; }
    if (t == 0) { bucket_start[NBUCK] = E_EDGES; offsets[N_NODES] = E_EDGES; }
}

// pass 1: scatter edges into bucket-contiguous tmp
__global__ __launch_bounds__(256) void sort_scatter1(
    const int* __restrict__ src, const int* __restrict__ dst,
    int* __restrict__ bucket_cursor, int2* __restrict__ tmp)
{
    __shared__ int ls[S1_CH];
    __shared__ int ld[S1_CH];
    __shared__ int cnt[NBUCK];
    const int t = threadIdx.x;
    for (int b = t; b < NBUCK; b += 256) cnt[b] = 0;
    __syncthreads();
    const int e0 = blockIdx.x * S1_CH;
    const int n = min(S1_CH, E_EDGES - e0);
    for (int i = t; i < n; i += 256) {
        int d = dst[e0 + i];
        ls[i] = src[e0 + i];
        ld[i] = d;
        atomicAdd(&cnt[d >> BSHIFT], 1);
    }
    __syncthreads();
    // claim per-block base in each bucket; reuse cnt[] as local cursor
    for (int b = t; b < NBUCK; b += 256) {
        int c = cnt[b];
        cnt[b] = c ? atomicAdd(&bucket_cursor[b], c) : 0;
    }
    __syncthreads();
    for (int i = t; i < n; i += 256) {
        int d = ld[i];
        int pos = atomicAdd(&cnt[d >> BSHIFT], 1);
        tmp[pos] = make_int2(ls[i], d);
    }
}

// pass 2: within-bucket counting sort + per-node offsets; one block per bucket
__global__ __launch_bounds__(256) void sort_scatter2(
    const int2* __restrict__ tmp, const int* __restrict__ bucket_start,
    int2* __restrict__ pedge, int* __restrict__ offsets)
{
    __shared__ int2 le[S2_CAP];
    __shared__ int cnt[256];
    __shared__ int s[256];
    __shared__ int cur[256];
    const int t = threadIdx.x;
    const int b = blockIdx.x;
    const int bstart = bucket_start[b];
    const int n = bucket_start[b + 1] - bstart;
    cnt[t] = 0;
    __syncthreads();
    for (int i = t; i < n; i += 256) {
        int2 e = tmp[bstart + i];
        if (i < S2_CAP) le[i] = e;
        atomicAdd(&cnt[e.y & 255], 1);
    }
    __syncthreads();
    int v = cnt[t];
    s[t] = v;
    __syncthreads();
    for (int off = 1; off < 256; off <<= 1) {
        int a = (t >= off) ? s[t - off] : 0;
        __syncthreads();
        s[t] += a;
        __syncthreads();
    }
    int excl = s[t] - v;
    int node = (b << BSHIFT) + t;
    if (node < N_NODES) offsets[node] = bstart + excl;
    cur[t] = excl;
    __syncthreads();
    for (int i = t; i < n; i += 256) {
        int2 e = (i < S2_CAP) ? le[i] : tmp[bstart + i];
        int pos = bstart + atomicAdd(&cur[e.y & 255], 1);
        pedge[pos] = e;
    }
}

// ================= edge scores + softmax + gather (unchanged) =================
constexpr int SC_BLOCKS = 1280;
__global__ __launch_bounds__(256) void edge_scores(
    const unsigned short* __restrict__ q, const unsigned short* __restrict__ k,
    const int2* __restrict__ pedge,
    float* __restrict__ scores, float2* __restrict__ block_ml)
{
    const int t = threadIdx.x;
    const int h = t & 7;
    const int step = SC_BLOCKS * 32;
    const int e0 = blockIdx.x * 32 + (t >> 3);
    float m = -1e30f, l = 0.f;
    for (int e = e0; e < E_EDGES; e += 4 * step) {
#pragma unroll
        for (int u = 0; u < 4; u++) {
            int ee = e + u * step;
            if (ee >= E_EDGES) break;
            int2 sd = pedge[ee];
            const uint4* qr = (const uint4*)(q + (size_t)sd.y * HCH + h * HDIM);
            const uint4* kr = (const uint4*)(k + (size_t)sd.x * HCH + h * HDIM);
            uint4 qa = qr[0], qb = qr[1];
            uint4 ka = kr[0], kb = kr[1];
            float acc = (bfdot8(qa, ka) + bfdot8(qb, kb)) * 0.25f;
            scores[(size_t)ee * 8 + h] = acc;
            float nm = fmaxf(m, acc);
            l = l * __expf(m - nm) + __expf(acc - nm);
            m = nm;
        }
    }
    __shared__ float sm[256], sl[256];
    sm[t] = m; sl[t] = l;
    __syncthreads();
    if (t < 8) {
        float M = -1e30f, L = 0.f;
        for (int i = t; i < 256; i += 8) {
            float mm = sm[i], ll = sl[i];
            float nm = fmaxf(M, mm);
            L = L * __expf(M - nm) + ll * __expf(mm - nm);
            M = nm;
        }
        block_ml[blockIdx.x * 8 + t] = make_float2(M, L);
    }
}

__global__ __launch_bounds__(256) void reduce_ml(
    const float2* __restrict__ block_ml, float2* __restrict__ head_ml, int nblk)
{
    const int t = threadIdx.x;
    float m = -1e30f, l = 0.f;
    for (int i = t; i < nblk * 8; i += 256) {
        float2 e = block_ml[i];
        float nm = fmaxf(m, e.x);
        l = l * __expf(m - nm) + e.y * __expf(e.x - nm);
        m = nm;
    }
    __shared__ float sm[256], sl[256];
    sm[t] = m; sl[t] = l;
    __syncthreads();
    if (t < 8) {
        float M = -1e30f, L = 0.f;
        for (int i = t; i < 256; i += 8) {
            float mm = sm[i], ll = sl[i];
            float nm = fmaxf(M, mm);
            L = L * __expf(M - nm) + ll * __expf(mm - nm);
            M = nm;
        }
        head_ml[t] = make_float2(M, 1.0f / L);
    }
}

__global__ __launch_bounds__(256) void edge_gather(
    const float* __restrict__ scores, const unsigned short* __restrict__ v,
    const int2* __restrict__ pedge, const int* __restrict__ offsets,
    const float2* __restrict__ head_ml, float* __restrict__ attended)
{
    const int t = threadIdx.x;
    const int lane = t & 63;
    const int d = blockIdx.x * 4 + (t >> 6);
    if (d >= N_NODES) return;
    const int h = lane >> 3;
    const float2 ml = head_ml[h];
    const float M = ml.x, invL = ml.y;
    const int start = offsets[d];
    const int end   = offsets[d + 1];
    float a0 = 0.f, a1 = 0.f;
    int i = start;
    for (; i + 3 < end; i += 4) {
        int2 sd0 = pedge[i], sd1 = pedge[i + 1], sd2 = pedge[i + 2], sd3 = pedge[i + 3];
        float s0 = scores[(size_t)(i) * 8 + h];
        float s1 = scores[(size_t)(i + 1) * 8 + h];
        float s2 = scores[(size_t)(i + 2) * 8 + h];
        float s3 = scores[(size_t)(i + 3) * 8 + h];
        uint v0 = *(const uint*)(v + (size_t)sd0.x * HCH + lane * 2);
        uint v1 = *(const uint*)(v + (size_t)sd1.x * HCH + lane * 2);
        uint v2 = *(const uint*)(v + (size_t)sd2.x * HCH + lane * 2);
        uint v3 = *(const uint*)(v + (size_t)sd3.x * HCH + lane * 2);
        float w0 = __expf(s0 - M), w1 = __expf(s1 - M);
        float w2 = __expf(s2 - M), w3 = __expf(s3 - M);
        a0 += w0 * bflo(v0) + w1 * bflo(v1) + w2 * bflo(v2) + w3 * bflo(v3);
        a1 += w0 * bfhi(v0) + w1 * bfhi(v1) + w2 * bfhi(v2) + w3 * bfhi(v3);
    }
    for (; i < end; i++) {
        int2 sd = pedge[i];
        float w = __expf(scores[(size_t)i * 8 + h] - M);
        uint vv = *(const uint*)(v + (size_t)sd.x * HCH + lane * 2);
        a0 += w * bflo(vv);
        a1 += w * bfhi(vv);
    }
    *(float2*)(attended + (size_t)d * HCH + lane * 2) = make_float2(a0 * invL, a1 * invL);
}

extern "C" void kernel_launch(void* const* d_in, const int* in_sizes, int n_in,
                              void* d_out, int out_size, void* d_ws, size_t ws_size,
                              hipStream_t stream)
{
    const float* x  = (const float*)d_in[0];
    const int* eidx = (const int*)d_in[1];
    const float* Wq = (const float*)d_in[2];
    const float* bq = (const float*)d_in[3];
    const float* Wk = (const float*)d_in[4];
    const float* bk = (const float*)d_in[5];
    const float* Wv = (const float*)d_in[6];
    const float* bv = (const float*)d_in[7];
    const float* Wo = (const float*)d_in[8];
    const float* bo = (const float*)d_in[9];
    float* out = (float*)d_out;

    char* ws = (char*)d_ws;
    constexpr size_t SZ_BF   = (size_t)N_NODES * HCH * 2;      // 25.6 MB
    constexpr size_t SZ_F32  = (size_t)N_NODES * HCH * 4;      // 51.2 MB
    constexpr size_t SZ_SC   = (size_t)E_EDGES * NHEADS * 4;   // 51.2 MB
    constexpr size_t SZ_PE   = (size_t)E_EDGES * sizeof(int2); // 12.8 MB
    size_t off = 0;
    unsigned short* q  = (unsigned short*)(ws + off); off += SZ_BF;
    unsigned short* k  = (unsigned short*)(ws + off); off += SZ_BF;
    unsigned short* v  = (unsigned short*)(ws + off); off += SZ_BF;
    float*  scores     = (float*)(ws + off);  off += SZ_SC;
    float*  attended   = (float*)(ws + off);  off += SZ_F32;
    int2*   pedge      = (int2*)(ws + off);   off += SZ_PE;
    int*    offsets    = (int*)(ws + off);    off += ((size_t)N_NODES + 1) * 4 + 4;
    int*    bucket_total  = (int*)(ws + off); off += (NBUCK + 1) * 4;
    int*    bucket_start  = (int*)(ws + off); off += (NBUCK + 1) * 4;
    int*    bucket_cursor = (int*)(ws + off); off += (NBUCK + 1) * 4;
    float2* block_ml   = (float2*)(ws + off); off += (size_t)SC_BLOCKS * 8 * sizeof(float2);
    float2* head_ml    = (float2*)(ws + off); off += 64;
    int2*   tmp        = (int2*)scores;   // scores region is dead until edge_scores
    const int* src = eidx;
    const int* dst = eidx + E_EDGES;

    dim3 blk(256);
    const int gblocks = (N_NODES + 63) / 64;

    gemm_qkv<<<dim3(gblocks, 3), blk, 0, stream>>>(x, Wq, Wk, Wv, bq, bk, bv, q, k, v, N_NODES);

    // two-pass bucketed counting sort by dst
    hipMemsetAsync(bucket_total, 0, (NBUCK + 1) * 4, stream);
    bucket_hist<<<S1_GRID, blk, 0, stream>>>(dst, bucket_total);
    bucket_scan<<<1, 512, 0, stream>>>(bucket_total, bucket_start, bucket_cursor, offsets);
    sort_scatter1<<<S1_GRID, blk, 0, stream>>>(src, dst, bucket_cursor, tmp);
    sort_scatter2<<<NBUCK, blk, 0, stream>>>(tmp, bucket_start, pedge, offsets);

    edge_scores<<<SC_BLOCKS, blk, 0, stream>>>(q, k, pedge, scores, block_ml);
    reduce_ml<<<1, blk, 0, stream>>>(block_ml, head_ml, SC_BLOCKS);
    edge_gather<<<(N_NODES + 3) / 4, blk, 0, stream>>>(scores, v, pedge, offsets, head_ml, attended);

    gemm_out<<<gblocks, blk, 0, stream>>>(attended, Wo, bo, x, out, N_NODES);
}

// Round 7
// 409.238 us; speedup vs baseline: 2.9946x; 1.0373x over previous
//
#include <hip/hip_runtime.h>
#include <cstdint>
#include <cstddef>

#define N_NODES 100000
#define E_EDGES 1600000
#define HCH 128
#define NHEADS 8
#define HDIM 16

typedef unsigned int uint;
typedef unsigned short ushort;
typedef __attribute__((ext_vector_type(8))) short short8;
typedef __attribute__((ext_vector_type(4))) float floatx4;

__device__ __forceinline__ ushort f2bf(float f) {
    uint u = __float_as_uint(f);
    u = (u + 0x7fff + ((u >> 16) & 1)) >> 16;
    return (ushort)u;
}
__device__ __forceinline__ float bflo(uint p) { return __uint_as_float(p << 16); }
__device__ __forceinline__ float bfhi(uint p) { return __uint_as_float(p & 0xffff0000u); }
__device__ __forceinline__ float bf2f(ushort s) { return __uint_as_float((uint)s << 16); }

__device__ __forceinline__ float bfdot8(uint4 a, uint4 b) {
    float s = bflo(a.x) * bflo(b.x) + bfhi(a.x) * bfhi(b.x);
    s += bflo(a.y) * bflo(b.y) + bfhi(a.y) * bfhi(b.y);
    s += bflo(a.z) * bflo(b.z) + bfhi(a.z) * bfhi(b.z);
    s += bflo(a.w) * bflo(b.w) + bfhi(a.w) * bfhi(b.w);
    return s;
}

// ================= MFMA GEMMs =================
#define LDSPAD 8
#define SMEM_BYTES (17408 + 34816)

__global__ __launch_bounds__(256) void gemm_qkv(
    const float* __restrict__ A,
    const float* __restrict__ Wq, const float* __restrict__ Wk, const float* __restrict__ Wv,
    const float* __restrict__ bq, const float* __restrict__ bk, const float* __restrict__ bv,
    ushort* __restrict__ qo, ushort* __restrict__ ko, ushort* __restrict__ vo,
    int M)
{
    __shared__ __align__(16) char smem[SMEM_BYTES];
    ushort (*As)[HCH + LDSPAD] = (ushort(*)[HCH + LDSPAD])smem;
    ushort (*Wt)[HCH + LDSPAD] = (ushort(*)[HCH + LDSPAD])(smem + 17408);
    float (*Cs)[132] = (float(*)[132])(smem + 17408);

    const int t = threadIdx.x;
    const int mb = blockIdx.x * 64;
    const float* W;
    const float* bias;
    ushort* out;
    if (blockIdx.y == 0)      { W = Wq; bias = bq; out = qo; }
    else if (blockIdx.y == 1) { W = Wk; bias = bk; out = ko; }
    else                      { W = Wv; bias = bv; out = vo; }

#pragma unroll
    for (int i = 0; i < 8; i++) {
        int p = t + i * 256;
        int row = p >> 5, c4 = p & 31;       // 32 float4 = 128 fp32 channels
        int g = mb + row;
        float4 a4 = make_float4(0.f, 0.f, 0.f, 0.f);
        if (g < M) a4 = *(const float4*)(A + (size_t)g * HCH + c4 * 4);
        uint lo = (uint)f2bf(a4.x) | ((uint)f2bf(a4.y) << 16);
        uint hi = (uint)f2bf(a4.z) | ((uint)f2bf(a4.w) << 16);
        *(uint2*)(&As[row][c4 * 4]) = make_uint2(lo, hi);
    }
#pragma unroll
    for (int i = 0; i < 16; i++) {
        int p = t + i * 256;
        int n = p & 127, k4 = p >> 7;
        float w0 = W[(size_t)(k4 * 4 + 0) * HCH + n];
        float w1 = W[(size_t)(k4 * 4 + 1) * HCH + n];
        float w2 = W[(size_t)(k4 * 4 + 2) * HCH + n];
        float w3 = W[(size_t)(k4 * 4 + 3) * HCH + n];
        uint lo = (uint)f2bf(w0) | ((uint)f2bf(w1) << 16);
        uint hi = (uint)f2bf(w2) | ((uint)f2bf(w3) << 16);
        *(uint2*)(&Wt[n][k4 * 4]) = make_uint2(lo, hi);
    }
    __syncthreads();

    const int lane = t & 63;
    const int w = t >> 6;
    const int m_l = lane & 15;
    const int q_l = lane >> 4;

    floatx4 acc[8];
#pragma unroll
    for (int tl = 0; tl < 8; tl++) acc[tl] = (floatx4){0.f, 0.f, 0.f, 0.f};

#pragma unroll
    for (int ks = 0; ks < HCH; ks += 32) {
        short8 af = *(const short8*)(&As[w * 16 + m_l][ks + q_l * 8]);
#pragma unroll
        for (int tl = 0; tl < 8; tl++) {
            short8 bf = *(const short8*)(&Wt[tl * 16 + m_l][ks + q_l * 8]);
            acc[tl] = __builtin_amdgcn_mfma_f32_16x16x32_bf16(af, bf, acc[tl], 0, 0, 0);
        }
    }
    __syncthreads();

#pragma unroll
    for (int tl = 0; tl < 8; tl++)
#pragma unroll
        for (int r = 0; r < 4; r++)
            Cs[w * 16 + q_l * 4 + r][tl * 16 + m_l] = acc[tl][r];
    __syncthreads();

#pragma unroll
    for (int i = 0; i < 8; i++) {
        int p = t + i * 256;
        int row = p >> 5, c4 = p & 31;
        int g = mb + row;
        if (g >= M) continue;
        float4 b4 = *(const float4*)(bias + c4 * 4);
        float v0 = Cs[row][c4 * 4 + 0] + b4.x;
        float v1 = Cs[row][c4 * 4 + 1] + b4.y;
        float v2 = Cs[row][c4 * 4 + 2] + b4.z;
        float v3 = Cs[row][c4 * 4 + 3] + b4.w;
        uint lo = (uint)f2bf(v0) | ((uint)f2bf(v1) << 16);
        uint hi = (uint)f2bf(v2) | ((uint)f2bf(v3) << 16);
        *(uint2*)(out + (size_t)g * HCH + c4 * 4) = make_uint2(lo, hi);
    }
}

// out = x + (attended_bf16_unnorm * invL[head]) @ Wo + bo
__global__ __launch_bounds__(256) void gemm_out(
    const ushort* __restrict__ A, const float* __restrict__ W,
    const float* __restrict__ bias, const float* __restrict__ res,
    const float* __restrict__ head_invl,
    float* __restrict__ C, int M)
{
    __shared__ __align__(16) char smem[SMEM_BYTES];
    ushort (*As)[HCH + LDSPAD] = (ushort(*)[HCH + LDSPAD])smem;
    ushort (*Wt)[HCH + LDSPAD] = (ushort(*)[HCH + LDSPAD])(smem + 17408);
    float (*Cs)[132] = (float(*)[132])(smem + 17408);

    const int t = threadIdx.x;
    const int mb = blockIdx.x * 64;

    __shared__ float invl_s[8];
    if (t < 8) invl_s[t] = head_invl[t];
    __syncthreads();

    // stage A: 64 rows x 64 uints (128 bf16 channels) = 2048 uint2 units
#pragma unroll
    for (int i = 0; i < 8; i++) {
        int p = t + i * 256;
        int row = p >> 5, cu2 = p & 31;     // 32 uint2 per row = 128 channels
        int g = mb + row;
        uint2 a = make_uint2(0, 0);
        if (g < M) a = *(const uint2*)(A + (size_t)g * HCH + cu2 * 4);
        float invl = invl_s[cu2 >> 2];      // 4 channels per uint2, 16 per head
        float f0 = bflo(a.x) * invl, f1 = bfhi(a.x) * invl;
        float f2 = bflo(a.y) * invl, f3 = bfhi(a.y) * invl;
        uint lo = (uint)f2bf(f0) | ((uint)f2bf(f1) << 16);
        uint hi = (uint)f2bf(f2) | ((uint)f2bf(f3) << 16);
        *(uint2*)(&As[row][cu2 * 4]) = make_uint2(lo, hi);
    }
#pragma unroll
    for (int i = 0; i < 16; i++) {
        int p = t + i * 256;
        int n = p & 127, k4 = p >> 7;
        float w0 = W[(size_t)(k4 * 4 + 0) * HCH + n];
        float w1 = W[(size_t)(k4 * 4 + 1) * HCH + n];
        float w2 = W[(size_t)(k4 * 4 + 2) * HCH + n];
        float w3 = W[(size_t)(k4 * 4 + 3) * HCH + n];
        uint lo = (uint)f2bf(w0) | ((uint)f2bf(w1) << 16);
        uint hi = (uint)f2bf(w2) | ((uint)f2bf(w3) << 16);
        *(uint2*)(&Wt[n][k4 * 4]) = make_uint2(lo, hi);
    }
    __syncthreads();

    const int lane = t & 63;
    const int w = t >> 6;
    const int m_l = lane & 15;
    const int q_l = lane >> 4;

    floatx4 acc[8];
#pragma unroll
    for (int tl = 0; tl < 8; tl++) acc[tl] = (floatx4){0.f, 0.f, 0.f, 0.f};

#pragma unroll
    for (int ks = 0; ks < HCH; ks += 32) {
        short8 af = *(const short8*)(&As[w * 16 + m_l][ks + q_l * 8]);
#pragma unroll
        for (int tl = 0; tl < 8; tl++) {
            short8 bf = *(const short8*)(&Wt[tl * 16 + m_l][ks + q_l * 8]);
            acc[tl] = __builtin_amdgcn_mfma_f32_16x16x32_bf16(af, bf, acc[tl], 0, 0, 0);
        }
    }
    __syncthreads();

#pragma unroll
    for (int tl = 0; tl < 8; tl++)
#pragma unroll
        for (int r = 0; r < 4; r++)
            Cs[w * 16 + q_l * 4 + r][tl * 16 + m_l] = acc[tl][r];
    __syncthreads();

#pragma unroll
    for (int i = 0; i < 8; i++) {
        int p = t + i * 256;
        int row = p >> 5, c4 = p & 31;
        int g = mb + row;
        if (g >= M) continue;
        float4 b4 = *(const float4*)(bias + c4 * 4);
        float4 r4 = *(const float4*)(res + (size_t)g * HCH + c4 * 4);
        float4 o;
        o.x = Cs[row][c4 * 4 + 0] + b4.x + r4.x;
        o.y = Cs[row][c4 * 4 + 1] + b4.y + r4.y;
        o.z = Cs[row][c4 * 4 + 2] + b4.z + r4.z;
        o.w = Cs[row][c4 * 4 + 3] + b4.w + r4.w;
        *(float4*)(C + (size_t)g * HCH + c4 * 4) = o;
    }
}

// ================= two-pass bucketed counting sort by dst =================
constexpr int BSHIFT = 8;
constexpr int NBUCK  = ((N_NODES - 1) >> BSHIFT) + 1;   // 391
constexpr int S1_GRID = 256;
constexpr int S1_CH   = (E_EDGES + S1_GRID - 1) / S1_GRID;  // 6250
constexpr int S2_CAP  = 6144;

__global__ __launch_bounds__(256) void bucket_hist(
    const int* __restrict__ dst, int* __restrict__ bucket_total)
{
    __shared__ int cnt[NBUCK];
    const int t = threadIdx.x;
    for (int b = t; b < NBUCK; b += 256) cnt[b] = 0;
    __syncthreads();
    const int e0 = blockIdx.x * S1_CH;
    const int n = min(S1_CH, E_EDGES - e0);
    for (int i = t; i < n; i += 256)
        atomicAdd(&cnt[dst[e0 + i] >> BSHIFT], 1);
    __syncthreads();
    for (int b = t; b < NBUCK; b += 256)
        if (cnt[b]) atomicAdd(&bucket_total[b], cnt[b]);
}

__global__ __launch_bounds__(512) void bucket_scan(
    const int* __restrict__ bucket_total, int* __restrict__ bucket_start,
    int* __restrict__ bucket_cursor, int* __restrict__ offsets)
{
    __shared__ int s[512];
    const int t = threadIdx.x;
    int v = (t < NBUCK) ? bucket_total[t] : 0;
    s[t] = v;
    __syncthreads();
    for (int off = 1; off < 512; off <<= 1) {
        int a = (t >= off) ? s[t - off] : 0;
        __syncthreads();
        s[t] += a;
        __syncthreads();
    }
    int excl = s[t] - v;
    if (t < NBUCK) { bucket_start[t] = excl; bucket_cursor[t] = excl; }
    if (t == 0) { bucket_start[NBUCK] = E_EDGES; offsets[N_NODES] = E_EDGES; }
}

__global__ __launch_bounds__(256) void sort_scatter1(
    const int* __restrict__ src, const int* __restrict__ dst,
    int* __restrict__ bucket_cursor, int2* __restrict__ tmp)
{
    __shared__ int ls[S1_CH];
    __shared__ int ld[S1_CH];
    __shared__ int cnt[NBUCK];
    const int t = threadIdx.x;
    for (int b = t; b < NBUCK; b += 256) cnt[b] = 0;
    __syncthreads();
    const int e0 = blockIdx.x * S1_CH;
    const int n = min(S1_CH, E_EDGES - e0);
    for (int i = t; i < n; i += 256) {
        int d = dst[e0 + i];
        ls[i] = src[e0 + i];
        ld[i] = d;
        atomicAdd(&cnt[d >> BSHIFT], 1);
    }
    __syncthreads();
    for (int b = t; b < NBUCK; b += 256) {
        int c = cnt[b];
        cnt[b] = c ? atomicAdd(&bucket_cursor[b], c) : 0;
    }
    __syncthreads();
    for (int i = t; i < n; i += 256) {
        int d = ld[i];
        int pos = atomicAdd(&cnt[d >> BSHIFT], 1);
        tmp[pos] = make_int2(ls[i], d);
    }
}

__global__ __launch_bounds__(256) void sort_scatter2(
    const int2* __restrict__ tmp, const int* __restrict__ bucket_start,
    int2* __restrict__ pedge, int* __restrict__ offsets)
{
    __shared__ int2 le[S2_CAP];
    __shared__ int cnt[256];
    __shared__ int s[256];
    __shared__ int cur[256];
    const int t = threadIdx.x;
    const int b = blockIdx.x;
    const int bstart = bucket_start[b];
    const int n = bucket_start[b + 1] - bstart;
    cnt[t] = 0;
    __syncthreads();
    for (int i = t; i < n; i += 256) {
        int2 e = tmp[bstart + i];
        if (i < S2_CAP) le[i] = e;
        atomicAdd(&cnt[e.y & 255], 1);
    }
    __syncthreads();
    int v = cnt[t];
    s[t] = v;
    __syncthreads();
    for (int off = 1; off < 256; off <<= 1) {
        int a = (t >= off) ? s[t - off] : 0;
        __syncthreads();
        s[t] += a;
        __syncthreads();
    }
    int excl = s[t] - v;
    int node = (b << BSHIFT) + t;
    if (node < N_NODES) offsets[node] = bstart + excl;
    cur[t] = excl;
    __syncthreads();
    for (int i = t; i < n; i += 256) {
        int2 e = (i < S2_CAP) ? le[i] : tmp[bstart + i];
        int pos = bstart + atomicAdd(&cur[e.y & 255], 1);
        pedge[pos] = e;
    }
}

// ============ edge scores: w = exp(q.k/4) stored bf16, per-block L sums ============
constexpr int SC_BLOCKS = 1280;
__global__ __launch_bounds__(256) void edge_scores(
    const ushort* __restrict__ q, const ushort* __restrict__ k,
    const int2* __restrict__ pedge,
    ushort* __restrict__ wout, float* __restrict__ block_l)
{
    const int t = threadIdx.x;
    const int h = t & 7;
    const int step = SC_BLOCKS * 32;
    const int e0 = blockIdx.x * 32 + (t >> 3);
    float lsum = 0.f;
    for (int e = e0; e < E_EDGES; e += 4 * step) {
#pragma unroll
        for (int u = 0; u < 4; u++) {
            int ee = e + u * step;
            if (ee >= E_EDGES) break;
            int2 sd = pedge[ee];
            const uint4* qr = (const uint4*)(q + (size_t)sd.y * HCH + h * HDIM);
            const uint4* kr = (const uint4*)(k + (size_t)sd.x * HCH + h * HDIM);
            uint4 qa = qr[0], qb = qr[1];
            uint4 ka = kr[0], kb = kr[1];
            float s = (bfdot8(qa, ka) + bfdot8(qb, kb)) * 0.25f;
            float w = __expf(s);       // global softmax: |s| small, no max-shift needed
            wout[(size_t)ee * 8 + h] = f2bf(w);
            lsum += w;
        }
    }
    __shared__ float sl[256];
    sl[t] = lsum;
    __syncthreads();
    if (t < 8) {
        float L = 0.f;
        for (int i = t; i < 256; i += 8) L += sl[i];
        block_l[blockIdx.x * 8 + t] = L;
    }
}

__global__ __launch_bounds__(256) void reduce_l(
    const float* __restrict__ block_l, float* __restrict__ head_invl, int nblk)
{
    const int t = threadIdx.x;
    float l = 0.f;
    for (int i = t; i < nblk * 8; i += 256) l += block_l[i];
    __shared__ float sl[256];
    sl[t] = l;
    __syncthreads();
    if (t < 8) {
        float L = 0.f;
        for (int i = t; i < 256; i += 8) L += sl[i];
        head_invl[t] = 1.0f / L;
    }
}

// ============ segment reduction: a[d] = sum w*v[src], unnormalized bf16 out ============
__global__ __launch_bounds__(256) void edge_gather(
    const ushort* __restrict__ wbuf, const ushort* __restrict__ v,
    const int2* __restrict__ pedge, const int* __restrict__ offsets,
    ushort* __restrict__ attended)
{
    const int t = threadIdx.x;
    const int lane = t & 63;
    const int d = blockIdx.x * 4 + (t >> 6);
    if (d >= N_NODES) return;
    const int h = lane >> 3;
    const int start = offsets[d];
    const int end   = offsets[d + 1];
    float a0 = 0.f, a1 = 0.f;
    int i = start;
    for (; i + 3 < end; i += 4) {
        int2 sd0 = pedge[i], sd1 = pedge[i + 1], sd2 = pedge[i + 2], sd3 = pedge[i + 3];
        float w0 = bf2f(wbuf[(size_t)(i) * 8 + h]);
        float w1 = bf2f(wbuf[(size_t)(i + 1) * 8 + h]);
        float w2 = bf2f(wbuf[(size_t)(i + 2) * 8 + h]);
        float w3 = bf2f(wbuf[(size_t)(i + 3) * 8 + h]);
        uint v0 = *(const uint*)(v + (size_t)sd0.x * HCH + lane * 2);
        uint v1 = *(const uint*)(v + (size_t)sd1.x * HCH + lane * 2);
        uint v2 = *(const uint*)(v + (size_t)sd2.x * HCH + lane * 2);
        uint v3 = *(const uint*)(v + (size_t)sd3.x * HCH + lane * 2);
        a0 += w0 * bflo(v0) + w1 * bflo(v1) + w2 * bflo(v2) + w3 * bflo(v3);
        a1 += w0 * bfhi(v0) + w1 * bfhi(v1) + w2 * bfhi(v2) + w3 * bfhi(v3);
    }
    for (; i < end; i++) {
        int2 sd = pedge[i];
        float w = bf2f(wbuf[(size_t)i * 8 + h]);
        uint vv = *(const uint*)(v + (size_t)sd.x * HCH + lane * 2);
        a0 += w * bflo(vv);
        a1 += w * bfhi(vv);
    }
    *(uint*)(attended + (size_t)d * HCH + lane * 2) =
        (uint)f2bf(a0) | ((uint)f2bf(a1) << 16);
}

extern "C" void kernel_launch(void* const* d_in, const int* in_sizes, int n_in,
                              void* d_out, int out_size, void* d_ws, size_t ws_size,
                              hipStream_t stream)
{
    const float* x  = (const float*)d_in[0];
    const int* eidx = (const int*)d_in[1];
    const float* Wq = (const float*)d_in[2];
    const float* bq = (const float*)d_in[3];
    const float* Wk = (const float*)d_in[4];
    const float* bk = (const float*)d_in[5];
    const float* Wv = (const float*)d_in[6];
    const float* bv = (const float*)d_in[7];
    const float* Wo = (const float*)d_in[8];
    const float* bo = (const float*)d_in[9];
    float* out = (float*)d_out;

    char* ws = (char*)d_ws;
    constexpr size_t SZ_BF   = (size_t)N_NODES * HCH * 2;      // 25.6 MB
    constexpr size_t SZ_W    = (size_t)E_EDGES * NHEADS * 2;   // 25.6 MB
    constexpr size_t SZ_PE   = (size_t)E_EDGES * sizeof(int2); // 12.8 MB
    size_t off = 0;
    ushort* q  = (ushort*)(ws + off); off += SZ_BF;
    ushort* k  = (ushort*)(ws + off); off += SZ_BF;
    ushort* v  = (ushort*)(ws + off); off += SZ_BF;
    ushort* wbuf = (ushort*)(ws + off); off += (SZ_W < SZ_PE ? SZ_PE : SZ_W); // aliased w/ tmp
    ushort* attended = (ushort*)(ws + off); off += SZ_BF;
    int2*   pedge    = (int2*)(ws + off);   off += SZ_PE;
    int*    offsets  = (int*)(ws + off);    off += ((size_t)N_NODES + 1) * 4 + 4;
    int*    bucket_total  = (int*)(ws + off); off += (NBUCK + 1) * 4;
    int*    bucket_start  = (int*)(ws + off); off += (NBUCK + 1) * 4;
    int*    bucket_cursor = (int*)(ws + off); off += (NBUCK + 1) * 4;
    float*  block_l   = (float*)(ws + off); off += (size_t)SC_BLOCKS * 8 * sizeof(float);
    float*  head_invl = (float*)(ws + off); off += 32;
    int2*   tmp       = (int2*)wbuf;   // wbuf region is dead until edge_scores
    const int* src = eidx;
    const int* dst = eidx + E_EDGES;

    dim3 blk(256);
    const int gblocks = (N_NODES + 63) / 64;

    gemm_qkv<<<dim3(gblocks, 3), blk, 0, stream>>>(x, Wq, Wk, Wv, bq, bk, bv, q, k, v, N_NODES);

    hipMemsetAsync(bucket_total, 0, (NBUCK + 1) * 4, stream);
    bucket_hist<<<S1_GRID, blk, 0, stream>>>(dst, bucket_total);
    bucket_scan<<<1, 512, 0, stream>>>(bucket_total, bucket_start, bucket_cursor, offsets);
    sort_scatter1<<<S1_GRID, blk, 0, stream>>>(src, dst, bucket_cursor, tmp);
    sort_scatter2<<<NBUCK, blk, 0, stream>>>(tmp, bucket_start, pedge, offsets);

    edge_scores<<<SC_BLOCKS, blk, 0, stream>>>(q, k, pedge, wbuf, block_l);
    reduce_l<<<1, blk, 0, stream>>>(block_l, head_invl, SC_BLOCKS);
    edge_gather<<<(N_NODES + 3) / 4, blk, 0, stream>>>(wbuf, v, pedge, offsets, attended);

    gemm_out<<<gblocks, blk, 0, stream>>>(attended, Wo, bo, x, head_invl, out, N_NODES);
}